// Round 12
// baseline (2243.782 us; speedup 1.0000x reference)
//
#include <hip/hip_runtime.h>

#define NN 100000
#define NE 400000
#define NB 4096
#define FN 78
#define FE 11
#define GD 256
#define NL 2
#define NT 2

typedef unsigned short u16;
typedef __attribute__((ext_vector_type(8))) short bf16x8;
typedef __attribute__((ext_vector_type(4))) float f32x4;

__device__ __forceinline__ float lrelu_(float x){ return x > 0.f ? x : 0.01f*x; }
__device__ __forceinline__ float elu_(float x){ return x > 0.f ? x : expf(x) - 1.f; }
__device__ __forceinline__ float sigm_(float x){ return 1.f/(1.f + expf(-x)); }

__device__ __forceinline__ float bf2f(u16 u){ return __uint_as_float(((unsigned)u) << 16); }
__device__ __forceinline__ u16 f2bf(float f){
  unsigned u = __float_as_uint(f);
  unsigned r = (u + 0x7fffu + ((u >> 16) & 1u)) >> 16;   // RNE
  return (u16)r;
}

__global__ void k_zero(float* p, size_t n){
  size_t i = (size_t)blockIdx.x*blockDim.x + threadIdx.x;
  size_t st = (size_t)gridDim.x*blockDim.x;
  for (; i < n; i += st) p[i] = 0.f;
}

// ---------------- CSR build (dst-sorted edge order) ----------------
__global__ void k_count(const int* __restrict__ dst, int* __restrict__ cnt, int E){
  int e = blockIdx.x*256 + threadIdx.x;
  if (e < E) atomicAdd(&cnt[dst[e]], 1);
}
__global__ void k_scan1(const int* __restrict__ cnt, int* __restrict__ part,
                        int* __restrict__ btot, int n){
  __shared__ int sd[256];
  int i = blockIdx.x*256 + threadIdx.x;
  int v = (i < n) ? cnt[i] : 0;
  sd[threadIdx.x] = v; __syncthreads();
  for (int d=1; d<256; d<<=1){
    int t = (threadIdx.x >= d) ? sd[threadIdx.x-d] : 0;
    __syncthreads();
    sd[threadIdx.x] += t;
    __syncthreads();
  }
  if (i < n) part[i] = sd[threadIdx.x];
  if (threadIdx.x == 255) btot[blockIdx.x] = sd[255];
}
__global__ void k_scan2(const int* __restrict__ btot, int* __restrict__ boff, int nb){
  __shared__ int sd[512];
  int tid = threadIdx.x;
  int v = (tid < nb) ? btot[tid] : 0;
  sd[tid] = v; __syncthreads();
  for (int d=1; d<512; d<<=1){
    int t = (tid >= d) ? sd[tid-d] : 0;
    __syncthreads();
    sd[tid] += t;
    __syncthreads();
  }
  if (tid < nb) boff[tid] = sd[tid] - v;   // exclusive
}
__global__ void k_scan3(const int* __restrict__ part, const int* __restrict__ boff,
                        int* __restrict__ rowptr, int n){
  int i = blockIdx.x*256 + threadIdx.x;
  if (i < n) rowptr[i+1] = part[i] + boff[blockIdx.x];
  if (i == 0) rowptr[0] = 0;
}
__global__ void k_cursor(const int* __restrict__ rowptr, int* __restrict__ cursor, int n){
  int i = blockIdx.x*256 + threadIdx.x;
  if (i < n) cursor[i] = rowptr[i];
}
__global__ void k_fill(const int* __restrict__ dst, int* __restrict__ cursor,
                       int* __restrict__ order, int E){
  int e = blockIdx.x*256 + threadIdx.x;
  if (e < E){
    int pos = atomicAdd(&cursor[dst[e]], 1);
    order[pos] = e;
  }
}
__global__ void k_gpb(const int* __restrict__ ng, int* __restrict__ gpb, int N, int B){
  int b = blockIdx.x*256 + threadIdx.x;
  if (b > B) return;
  int lo = 0, hi = N;
  while (lo < hi){ int mid = (lo+hi)>>1; if (ng[mid] < b) lo = mid+1; else hi = mid; }
  gpb[b] = lo;
}

// Pack W[OUT][K] f32 -> bf16 B-fragment order
__global__ void k_pack_b(const float* __restrict__ W, u16* __restrict__ Bp, int OUT, int K){
  int t = blockIdx.x*256 + threadIdx.x;
  if (t >= OUT*K) return;
  int j = t & 7;
  int l = (t >> 3) & 63;
  int rest = t >> 9;
  int nks = K >> 5;
  int ks = rest % nks, c = rest / nks;
  int col = c*16 + (l & 15);
  int k = ks*32 + (l >> 4)*8 + j;
  Bp[t] = f2bf(W[(size_t)col*K + k]);
}

// Pack r,z gates of (Wih,Whh) into one K=512 B-matrix, r/z interleaved per 16-col group
__global__ void k_pack_rz(const float* __restrict__ Wih, const float* __restrict__ Whh,
                          u16* __restrict__ Bp){
  int t = blockIdx.x*256 + threadIdx.x;   // grid covers 512*512
  int j = t & 7;
  int l = (t >> 3) & 63;
  int rest = t >> 9;
  int ks = rest & 15, c = rest >> 4;      // nks = 16
  int srcrow = (c & 1)*256 + (c >> 1)*16 + (l & 15);
  int k = ks*32 + (l >> 4)*8 + j;
  float v = (k < 256) ? Wih[(size_t)srcrow*GD + k] : Whh[(size_t)srcrow*GD + (k - 256)];
  Bp[t] = f2bf(v);
}

// Y[r][j] = act( sum_{k<78} X[r][k]*W[j*ldw+k] + b[j] )  -> bf16 out
template<int TN>
__global__ void k_node_proj(const float* __restrict__ nf, const float* __restrict__ W, int ldw,
                            const float* __restrict__ b, int act, u16* __restrict__ outb, int N){
  __shared__ float sx[TN][FN];
  int base = blockIdx.x*TN, tid = threadIdx.x;
  for (int i = tid; i < TN*FN; i += 256){
    int n = i / FN, k = i % FN;
    int row = base + n;
    sx[n][k] = (row < N) ? nf[(size_t)row*FN + k] : 0.f;
  }
  __syncthreads();
  int j = tid;
  float acc[TN];
  #pragma unroll
  for (int n=0;n<TN;n++) acc[n]=0.f;
  for (int k=0;k<FN;k++){
    float w = W[(size_t)j*ldw + k];
    #pragma unroll
    for (int n=0;n<TN;n++) acc[n] += w*sx[n][k];
  }
  float bb = b ? b[j] : 0.f;
  #pragma unroll
  for (int n=0;n<TN;n++){
    int row = base + n;
    if (row < N){
      float v = acc[n] + bb;
      outb[(size_t)row*GD + j] = f2bf(act ? lrelu_(v) : v);
    }
  }
}

// ---- per-node dot kernels ----
__global__ void k_dot2_bf16(const u16* __restrict__ rows, const float* __restrict__ wv,
                            float* __restrict__ za, float* __restrict__ zb, int N){
  int wav = threadIdx.x >> 6, lane = threadIdx.x & 63;
  int i = blockIdx.x*4 + wav;
  if (i >= N) return;
  int c0 = lane*4;
  ushort4 r4 = *(const ushort4*)&rows[(size_t)i*GD + c0];
  float4 wa = *(const float4*)&wv[c0];
  float4 wb = *(const float4*)&wv[GD + c0];
  float v0 = bf2f(r4.x), v1 = bf2f(r4.y), v2 = bf2f(r4.z), v3 = bf2f(r4.w);
  float va = v0*wa.x + v1*wa.y + v2*wa.z + v3*wa.w;
  float vb = v0*wb.x + v1*wb.y + v2*wb.z + v3*wb.w;
  #pragma unroll
  for (int off=32; off; off>>=1){ va += __shfl_down(va, off); vb += __shfl_down(vb, off); }
  if (lane == 0){ za[i] = va; zb[i] = vb; }
}

__global__ void k_dot1_bf16(const u16* __restrict__ rows, const float* __restrict__ wv,
                            float* __restrict__ z, int N){
  int wav = threadIdx.x >> 6, lane = threadIdx.x & 63;
  int i = blockIdx.x*4 + wav;
  if (i >= N) return;
  int c0 = lane*4;
  ushort4 r4 = *(const ushort4*)&rows[(size_t)i*GD + c0];
  float4 wa = *(const float4*)&wv[c0];
  float va = bf2f(r4.x)*wa.x + bf2f(r4.y)*wa.y + bf2f(r4.z)*wa.z + bf2f(r4.w)*wa.w;
  #pragma unroll
  for (int off=32; off; off>>=1) va += __shfl_down(va, off);
  if (lane == 0) z[i] = va;
}

__global__ void k_dotg_relu(const float* __restrict__ g, const float* __restrict__ wv,
                            float* __restrict__ zg, int B){
  int wav = threadIdx.x >> 6, lane = threadIdx.x & 63;
  int i = blockIdx.x*4 + wav;
  if (i >= B) return;
  int c0 = lane*4;
  float4 gv = *(const float4*)&g[(size_t)i*GD + c0];
  float4 wa = *(const float4*)&wv[c0];
  float va = fmaxf(gv.x,0.f)*wa.x + fmaxf(gv.y,0.f)*wa.y + fmaxf(gv.z,0.f)*wa.z + fmaxf(gv.w,0.f)*wa.w;
  #pragma unroll
  for (int off=32; off; off>>=1) va += __shfl_down(va, off);
  if (lane == 0) zg[i] = va;
}

// ---- GetContext fused (online softmax, manual prefetch of next edge's P row + ef) ----
__global__ void __launch_bounds__(256)
k_ctx_fused(const u16* __restrict__ P, const float* __restrict__ za,
            const int* __restrict__ order, const int* __restrict__ rowptr,
            const int* __restrict__ src, const float* __restrict__ ef,
            const float* __restrict__ Wpe1, const float* __restrict__ bpe1,
            const float* __restrict__ Wpe2, const float* __restrict__ bpe2,
            u16* __restrict__ wc, float* __restrict__ sdeg, int N){
  int wv = threadIdx.x >> 6, lane = threadIdx.x & 63;
  int d = blockIdx.x*4 + wv;
  if (d >= N) return;
  int j0 = rowptr[d], j1 = rowptr[d+1];
  int c0 = lane*4;
  float wb0 = Wpe2[GD+c0], wb1 = Wpe2[GD+c0+1], wb2 = Wpe2[GD+c0+2], wb3 = Wpe2[GD+c0+3];
  float bp0 = bpe1[c0], bp1 = bpe1[c0+1], bp2 = bpe1[c0+2], bp3 = bpe1[c0+3];
  float wk0[FE], wk1[FE], wk2[FE], wk3[FE];
  #pragma unroll
  for (int k=0;k<FE;k++){
    wk0[k] = Wpe1[(size_t)(c0+0)*(FN+FE) + FN + k];
    wk1[k] = Wpe1[(size_t)(c0+1)*(FN+FE) + FN + k];
    wk2[k] = Wpe1[(size_t)(c0+2)*(FN+FE) + FN + k];
    wk3[k] = Wpe1[(size_t)(c0+3)*(FN+FE) + FN + k];
  }
  float zad = za[d] + bpe2[0];
  float m = -1e30f, s = 0.f;
  float a0=0.f, a1=0.f, a2=0.f, a3=0.f;
  ushort4 p4c = make_ushort4(0,0,0,0);
  float efc[FE];
  #pragma unroll
  for (int k=0;k<FE;k++) efc[k] = 0.f;
  if (j0 < j1){
    int e0 = order[j0];
    p4c = *(const ushort4*)&P[(size_t)src[e0]*GD + c0];
    const float* efp = &ef[(size_t)e0*FE];
    #pragma unroll
    for (int k=0;k<FE;k++) efc[k] = efp[k];
  }
  for (int j=j0; j<j1; j++){
    // prefetch next edge before this edge's compute
    ushort4 p4n = p4c;
    float efn[FE];
    #pragma unroll
    for (int k=0;k<FE;k++) efn[k] = 0.f;
    if (j+1 < j1){
      int en = order[j+1];
      p4n = *(const ushort4*)&P[(size_t)src[en]*GD + c0];
      const float* efp = &ef[(size_t)en*FE];
      #pragma unroll
      for (int k=0;k<FE;k++) efn[k] = efp[k];
    }
    float h0 = bf2f(p4c.x)+bp0, h1 = bf2f(p4c.y)+bp1, h2 = bf2f(p4c.z)+bp2, h3 = bf2f(p4c.w)+bp3;
    #pragma unroll
    for (int k=0;k<FE;k++){
      h0 += wk0[k]*efc[k]; h1 += wk1[k]*efc[k]; h2 += wk2[k]*efc[k]; h3 += wk3[k]*efc[k];
    }
    h0 = lrelu_(h0); h1 = lrelu_(h1); h2 = lrelu_(h2); h3 = lrelu_(h3);
    float part = h0*wb0 + h1*wb1 + h2*wb2 + h3*wb3;
    #pragma unroll
    for (int off=32; off; off>>=1) part += __shfl_down(part, off);
    float l = lrelu_(part + zad);
    l = __shfl(l, 0);
    float mn = fmaxf(m, l);
    float sc = __expf(m - mn);
    float p  = __expf(l - mn);
    s = s*sc + p;
    a0 = a0*sc + p*h0; a1 = a1*sc + p*h1; a2 = a2*sc + p*h2; a3 = a3*sc + p*h3;
    m = mn;
    p4c = p4n;
    #pragma unroll
    for (int k=0;k<FE;k++) efc[k] = efn[k];
  }
  float inv = (j1 > j0) ? 1.f/s : 0.f;
  ushort4 o;
  o.x = f2bf(a0*inv); o.y = f2bf(a1*inv); o.z = f2bf(a2*inv); o.w = f2bf(a3*inv);
  *(ushort4*)&wc[(size_t)d*GD + c0] = o;
  if (lane == 0) sdeg[d] = (j1 > j0) ? 1.f : 0.f;
}

// ---- GNN layer fused, TWO-PASS (logits scalar-only -> no rescale chain) ----
__global__ void __launch_bounds__(256)
k_gnn_fused(const u16* __restrict__ hv, const float* __restrict__ za, const float* __restrict__ zb,
            const int* __restrict__ order, const int* __restrict__ rowptr,
            const int* __restrict__ src, const float* __restrict__ bias,
            u16* __restrict__ cw, int N){
  int wv = threadIdx.x >> 6, lane = threadIdx.x & 63;
  int d = blockIdx.x*4 + wv;
  if (d >= N) return;
  int j0 = rowptr[d], j1 = rowptr[d+1];
  int c0 = lane*4;
  float zad = za[d] + bias[0];
  // pass 1: max over scalar logits (4B loads only)
  float M = -1e30f;
  for (int j=j0; j<j1; j++){
    int sn = src[order[j]];
    M = fmaxf(M, lrelu_(zad + zb[sn]));
  }
  // pass 2: accumulate without rescale -> row gathers fully overlap
  float s = 0.f;
  float a0=0.f, a1=0.f, a2=0.f, a3=0.f;
  for (int j=j0; j<j1; j++){
    int e = order[j];
    int sn = src[e];
    float p = __expf(lrelu_(zad + zb[sn]) - M);
    ushort4 r4 = *(const ushort4*)&hv[(size_t)sn*GD + c0];
    s += p;
    a0 += p*bf2f(r4.x);
    a1 += p*bf2f(r4.y);
    a2 += p*bf2f(r4.z);
    a3 += p*bf2f(r4.w);
  }
  float inv = (j1 > j0) ? 1.f/s : 0.f;
  ushort4 o;
  o.x = f2bf(elu_(a0*inv)); o.y = f2bf(elu_(a1*inv));
  o.z = f2bf(elu_(a2*inv)); o.w = f2bf(elu_(a3*inv));
  *(ushort4*)&cw[(size_t)d*GD + c0] = o;
}

// ---- readout fused ----
__global__ void __launch_bounds__(256)
k_ro_fused(const u16* __restrict__ hv, const float* __restrict__ zg, const float* __restrict__ zh,
           const int* __restrict__ gpb, const float* __restrict__ bias,
           float* __restrict__ gr, int B){
  int b = blockIdx.x, tid = threadIdx.x;
  int i0 = gpb[b], i1 = gpb[b+1];
  float zgb = zg[b] + bias[0];
  __shared__ float red[256];
  float lm = -1e30f;
  for (int i = i0 + tid; i < i1; i += 256) lm = fmaxf(lm, lrelu_(zgb + zh[i]));
  red[tid] = lm; __syncthreads();
  for (int d2=128; d2; d2>>=1){ if (tid < d2) red[tid] = fmaxf(red[tid], red[tid+d2]); __syncthreads(); }
  float M = red[0]; __syncthreads();
  float ls = 0.f;
  for (int i = i0 + tid; i < i1; i += 256) ls += __expf(lrelu_(zgb + zh[i]) - M);
  red[tid] = ls; __syncthreads();
  for (int d2=128; d2; d2>>=1){ if (tid < d2) red[tid] += red[tid+d2]; __syncthreads(); }
  float S = red[0];
  float acc = 0.f;
  for (int i = i0; i < i1; i++){
    float p = __expf(lrelu_(zgb + zh[i]) - M);
    acc += p * bf2f(hv[(size_t)i*GD + tid]);
  }
  gr[(size_t)b*GD + tid] = (i1 > i0) ? acc/S : 0.f;
}

__global__ void k_segsum_sorted(const u16* __restrict__ h, const int* __restrict__ gpb,
                                float* __restrict__ g, int B){
  int b = blockIdx.x, tid = threadIdx.x;
  int i0 = gpb[b], i1 = gpb[b+1];
  float acc = 0.f;
  for (int i = i0; i < i1; i++) acc += bf2f(h[(size_t)i*GD + tid]);
  g[(size_t)b*GD + tid] = acc;
}

// ---- 32-row MFMA GRU with fused r/z gates (K=512 concat) ----
// wave id via readfirstlane -> weight addresses wave-uniform -> saddr loads.
__global__ void __launch_bounds__(512)
k_gru_mfma32(const u16* __restrict__ x, const u16* __restrict__ hprev,
             const u16* __restrict__ rzp, const u16* __restrict__ nip, const u16* __restrict__ nhp,
             const float* __restrict__ bih, const float* __restrict__ bhh,
             u16* __restrict__ hout, int R){
  int tid = threadIdx.x;
  int wv = __builtin_amdgcn_readfirstlane(tid >> 6);
  int lane = tid & 63;
  int m = lane & 15, kg = lane >> 4;
  int r0 = blockIdx.x*32;   // R must be a multiple of 32 (100000 = 3125*32)

  f32x4 arz[2][4], ani[2][2], anh[2][2];
  #pragma unroll
  for (int rt=0;rt<2;rt++){
    #pragma unroll
    for (int t=0;t<4;t++) arz[rt][t] = (f32x4)(0.f);
    #pragma unroll
    for (int t=0;t<2;t++){ ani[rt][t] = (f32x4)(0.f); anh[rt][t] = (f32x4)(0.f); }
  }

  #pragma unroll
  for (int ks=0; ks<8; ks++){
    int koff = ks*32 + kg*8;
    bf16x8 ax[2], ah[2];
    #pragma unroll
    for (int rt=0; rt<2; rt++){
      int row = r0 + rt*16 + m;
      ax[rt] = *(const bf16x8*)&x[(size_t)row*GD + koff];
      ah[rt] = *(const bf16x8*)&hprev[(size_t)row*GD + koff];
    }
    // rz: K=512 (x rows at kidx=ks, h rows at kidx=ks+8)
    #pragma unroll
    for (int t=0;t<4;t++){
      int c = wv*4 + t;
      bf16x8 bx = *(const bf16x8*)&rzp[(size_t)((c*16 + ks    )*64 + lane)*8];
      bf16x8 bh = *(const bf16x8*)&rzp[(size_t)((c*16 + ks + 8)*64 + lane)*8];
      #pragma unroll
      for (int rt=0; rt<2; rt++){
        arz[rt][t] = __builtin_amdgcn_mfma_f32_16x16x32_bf16(ax[rt], bx, arz[rt][t], 0, 0, 0);
        arz[rt][t] = __builtin_amdgcn_mfma_f32_16x16x32_bf16(ah[rt], bh, arz[rt][t], 0, 0, 0);
      }
    }
    // n gates: separate gi2 (x) and gh2 (h), K=256
    #pragma unroll
    for (int t=0;t<2;t++){
      int c = wv*2 + t;
      bf16x8 bi = *(const bf16x8*)&nip[(size_t)((c*8 + ks)*64 + lane)*8];
      bf16x8 bh = *(const bf16x8*)&nhp[(size_t)((c*8 + ks)*64 + lane)*8];
      #pragma unroll
      for (int rt=0; rt<2; rt++){
        ani[rt][t] = __builtin_amdgcn_mfma_f32_16x16x32_bf16(ax[rt], bi, ani[rt][t], 0, 0, 0);
        anh[rt][t] = __builtin_amdgcn_mfma_f32_16x16x32_bf16(ah[rt], bh, anh[rt][t], 0, 0, 0);
      }
    }
  }

  #pragma unroll
  for (int g=0; g<2; g++){
    int ch = (wv*2 + g)*16 + m;
    float brz_r = bih[ch] + bhh[ch];
    float brz_z = bih[ch+GD] + bhh[ch+GD];
    float bin   = bih[ch+2*GD];
    float bhn   = bhh[ch+2*GD];
    #pragma unroll
    for (int rt=0; rt<2; rt++){
      #pragma unroll
      for (int i=0;i<4;i++){
        int row = r0 + rt*16 + kg*4 + i;
        float rr = sigm_(arz[rt][2*g  ][i] + brz_r);
        float zz = sigm_(arz[rt][2*g+1][i] + brz_z);
        float nn = tanhf(ani[rt][g][i] + bin + rr*(anh[rt][g][i] + bhn));
        float hp = bf2f(hprev[(size_t)row*GD + ch]);
        float o = (1.f - zz)*nn + zz*hp;
        hout[(size_t)row*GD + ch] = f2bf(fmaxf(o, 0.f));
      }
    }
  }
}

// ---- 64-row MFMA projection: Y = X@W^T + b, optional mask+elu epilogue ----
template<int DO_ELU>
__global__ void __launch_bounds__(512)
k_proj_mfma64(const u16* __restrict__ X, const u16* __restrict__ Wp,
              const float* __restrict__ b, u16* __restrict__ Y, int R,
              const float* __restrict__ mask){
  int tid = threadIdx.x;
  int wv = __builtin_amdgcn_readfirstlane(tid >> 6);
  int lane = tid & 63;
  int m = lane & 15, kg = lane >> 4;
  int r0 = blockIdx.x*64;
  f32x4 acc[2][4];
  #pragma unroll
  for (int t=0;t<2;t++)
    #pragma unroll
    for (int rt=0;rt<4;rt++) acc[t][rt] = (f32x4)(0.f);
  #pragma unroll
  for (int ks=0; ks<8; ks++){
    int koff = ks*32 + kg*8;
    bf16x8 a[4];
    #pragma unroll
    for (int rt=0; rt<4; rt++){
      int row = r0 + rt*16 + m;
      if (row > R-1) row = R-1;
      a[rt] = *(const bf16x8*)&X[(size_t)row*GD + koff];
    }
    #pragma unroll
    for (int t=0;t<2;t++){
      int c = wv*2 + t;
      bf16x8 bv = *(const bf16x8*)&Wp[(size_t)((c*8 + ks)*64 + lane)*8];
      #pragma unroll
      for (int rt=0; rt<4; rt++)
        acc[t][rt] = __builtin_amdgcn_mfma_f32_16x16x32_bf16(a[rt], bv, acc[t][rt], 0, 0, 0);
    }
  }
  #pragma unroll
  for (int t=0;t<2;t++){
    int col = wv*32 + t*16 + m;
    float bb = b[col];
    #pragma unroll
    for (int rt=0; rt<4; rt++){
      #pragma unroll
      for (int i=0;i<4;i++){
        int row = r0 + rt*16 + kg*4 + i;
        if (row < R){
          float v = acc[t][rt][i] + bb;
          if (DO_ELU){
            float mk = (mask[row] > 0.f) ? 1.f : 0.f;
            v = elu_(v*mk);
          }
          Y[(size_t)row*GD + col] = f2bf(v);
        }
      }
    }
  }
}

// ---- 16-row MFMA GRU for readout (f32 in/out, elu applied here) ----
__global__ void __launch_bounds__(256)
k_gru_mfma_f32(const float* __restrict__ x, const float* __restrict__ hprev,
               const u16* __restrict__ Wihp, const u16* __restrict__ Whhp,
               const float* __restrict__ bih, const float* __restrict__ bhh,
               float* __restrict__ hout, int R){
  int tid = threadIdx.x;
  int wave = __builtin_amdgcn_readfirstlane(tid >> 6);
  int lane = tid & 63;
  int m = lane & 15, kg = lane >> 4;
  int r0 = blockIdx.x*16;

  f32x4 agi[3][4], agh[3][4];
  #pragma unroll
  for (int g=0;g<3;g++)
    #pragma unroll
    for (int t=0;t<4;t++){ agi[g][t] = (f32x4)(0.f); agh[g][t] = (f32x4)(0.f); }

  #pragma unroll
  for (int ks=0; ks<8; ks++){
    int koff = ks*32 + kg*8;
    const float* xp = x + (size_t)(r0 + m)*GD + koff;
    float4 x0 = *(const float4*)xp;
    float4 x1 = *(const float4*)(xp+4);
    bf16x8 ax;
    ax[0]=(short)f2bf(elu_(x0.x)); ax[1]=(short)f2bf(elu_(x0.y));
    ax[2]=(short)f2bf(elu_(x0.z)); ax[3]=(short)f2bf(elu_(x0.w));
    ax[4]=(short)f2bf(elu_(x1.x)); ax[5]=(short)f2bf(elu_(x1.y));
    ax[6]=(short)f2bf(elu_(x1.z)); ax[7]=(short)f2bf(elu_(x1.w));
    const float* hr = hprev + (size_t)(r0 + m)*GD + koff;
    float4 h0 = *(const float4*)hr;
    float4 h1 = *(const float4*)(hr+4);
    bf16x8 ah;
    ah[0]=(short)f2bf(h0.x); ah[1]=(short)f2bf(h0.y); ah[2]=(short)f2bf(h0.z); ah[3]=(short)f2bf(h0.w);
    ah[4]=(short)f2bf(h1.x); ah[5]=(short)f2bf(h1.y); ah[6]=(short)f2bf(h1.z); ah[7]=(short)f2bf(h1.w);
    #pragma unroll
    for (int g=0;g<3;g++){
      #pragma unroll
      for (int t=0;t<4;t++){
        int c = g*16 + wave*4 + t;
        bf16x8 bi = *(const bf16x8*)&Wihp[(size_t)((c*8 + ks)*64 + lane)*8];
        bf16x8 bh = *(const bf16x8*)&Whhp[(size_t)((c*8 + ks)*64 + lane)*8];
        agi[g][t] = __builtin_amdgcn_mfma_f32_16x16x32_bf16(ax, bi, agi[g][t], 0, 0, 0);
        agh[g][t] = __builtin_amdgcn_mfma_f32_16x16x32_bf16(ah, bh, agh[g][t], 0, 0, 0);
      }
    }
  }
  #pragma unroll
  for (int t=0;t<4;t++){
    int col = wave*64 + t*16 + m;
    float bir = bih[col],      bhr = bhh[col];
    float biz = bih[col+GD],   bhz = bhh[col+GD];
    float bin = bih[col+2*GD], bhn = bhh[col+2*GD];
    #pragma unroll
    for (int i=0;i<4;i++){
      int row = r0 + kg*4 + i;
      float rr = sigm_(agi[0][t][i] + bir + agh[0][t][i] + bhr);
      float zz = sigm_(agi[1][t][i] + biz + agh[1][t][i] + bhz);
      float nn = tanhf(agi[2][t][i] + bin + rr*(agh[2][t][i] + bhn));
      float hp = hprev[(size_t)row*GD + col];
      float o = (1.f - zz)*nn + zz*hp;
      hout[(size_t)row*GD + col] = fmaxf(o, 0.f);
    }
  }
}

__global__ void k_layernorm(const float* __restrict__ gb, const float* __restrict__ gamma,
                            const float* __restrict__ beta, float* __restrict__ outb){
  int r = blockIdx.x, j = threadIdx.x;
  float v = gb[(size_t)r*GD + j];
  float s1 = v, s2 = v*v;
  #pragma unroll
  for (int off=32; off; off>>=1){ s1 += __shfl_down(s1, off); s2 += __shfl_down(s2, off); }
  __shared__ float r1[4], r2[4];
  int wv = j >> 6, lane = j & 63;
  if (lane == 0){ r1[wv] = s1; r2[wv] = s2; }
  __syncthreads();
  float S1 = r1[0]+r1[1]+r1[2]+r1[3];
  float S2 = r2[0]+r2[1]+r2[2]+r2[3];
  float mu = S1/(float)GD;
  float var = fmaxf(S2/(float)GD - mu*mu, 0.f);
  outb[(size_t)r*GD + j] = (v - mu)/sqrtf(var + 1e-5f)*gamma[j] + beta[j];
}

extern "C" void kernel_launch(void* const* d_in, const int* in_sizes, int n_in,
                              void* d_out, int out_size, void* d_ws, size_t ws_size,
                              hipStream_t stream){
  const float* node_feats = (const float*)d_in[0];
  const float* edge_feats = (const float*)d_in[1];
  const int*   src        = (const int*)d_in[2];
  const int*   dst        = (const int*)d_in[3];
  const int*   node_graph = (const int*)d_in[4];
  const float* W_pn   = (const float*)d_in[5];
  const float* b_pn   = (const float*)d_in[6];
  const float* W_pe1  = (const float*)d_in[7];
  const float* b_pe1  = (const float*)d_in[8];
  const float* W_pe2  = (const float*)d_in[9];
  const float* b_pe2  = (const float*)d_in[10];
  const float* W_et   = (const float*)d_in[11];
  const float* b_et   = (const float*)d_in[12];
  const float* g0_Wih = (const float*)d_in[13];
  const float* g0_Whh = (const float*)d_in[14];
  const float* g0_bih = (const float*)d_in[15];
  const float* g0_bhh = (const float*)d_in[16];
  const float* gnn_W_pe = (const float*)d_in[17];
  const float* gnn_b_pe = (const float*)d_in[18];
  const float* gnn_W_pn = (const float*)d_in[19];
  const float* gnn_b_pn = (const float*)d_in[20];
  const float* gnn_Wih  = (const float*)d_in[21];
  const float* gnn_Whh  = (const float*)d_in[22];
  const float* gnn_bih  = (const float*)d_in[23];
  const float* gnn_bhh  = (const float*)d_in[24];
  const float* ro_W_cl = (const float*)d_in[25];
  const float* ro_b_cl = (const float*)d_in[26];
  const float* ro_W_pn = (const float*)d_in[27];
  const float* ro_b_pn = (const float*)d_in[28];
  const float* ro_Wih  = (const float*)d_in[29];
  const float* ro_Whh  = (const float*)d_in[30];
  const float* ro_bih  = (const float*)d_in[31];
  const float* ro_bhh  = (const float*)d_in[32];
  const float* ln_gamma = (const float*)d_in[33];
  const float* ln_beta  = (const float*)d_in[34];
  float* outp = (float*)d_out;

  const int NBLK = (NN + 255)/256;

  // ---- workspace layout ----
  char* w = (char*)d_ws;
  size_t need = 0;
  float* gbuf  = (float*)(w + need); need += (size_t)NB*GD*4;
  float* grbuf = (float*)(w + need); need += (size_t)NB*GD*4;
  float* za    = (float*)(w + need); need += (size_t)NN*4;
  float* zb    = (float*)(w + need); need += (size_t)NN*4;
  float* zg    = (float*)(w + need); need += (size_t)NB*4;
  float* sdeg  = (float*)(w + need); need += (size_t)NN*4;
  int*   cnt    = (int*)(w + need); need += (size_t)NN*4;
  int*   rowptr = (int*)(w + need); need += (size_t)(NN+1)*4;
  int*   cursor = (int*)(w + need); need += (size_t)NN*4;
  int*   order  = (int*)(w + need); need += (size_t)NE*4;
  int*   gpb    = (int*)(w + need); need += (size_t)(NB+1)*4;
  int*   btot   = (int*)(w + need); need += (size_t)512*4;
  int*   boff   = (int*)(w + need); need += (size_t)512*4;
  u16*   hbuf = (u16*)(w + need); need += (size_t)NN*GD*2;
  u16*   htmp = (u16*)(w + need); need += (size_t)NN*GD*2;
  u16*   cwb  = (u16*)(w + need); need += (size_t)NN*GD*2;
  u16*   dbuf = (u16*)(w + need); need += (size_t)NN*GD*2;
  u16* pGruN = (u16*)(w + need); need += (size_t)3*393216*2;  // g0, gnn0, gnn1 (rz+ni+nh)
  u16* pGruR = (u16*)(w + need); need += (size_t)4*196608*2;  // ro Wih/Whh x2 (old format)
  u16* pPn  = (u16*)(w + need); need += (size_t)4*GD*GD*2;
  u16* pEt  = (u16*)(w + need); need += (size_t)GD*GD*2;
  if (ws_size < need) return;
  u16* Pbuf   = hbuf;
  u16* hv_new = htmp;

  const size_t LW = 393216;          // per-layer new-format pack (rz 262144 + ni 65536 + nh 65536)
  const size_t OW = 196608;          // old-format 768x256 pack
  const size_t PW = (size_t)GD*GD;
  const int G64 = (NN + 63)/64;
  const int G32 = NN/32;             // 100000/32 = 3125 exact

  // ---- CSR build + graph rowptr ----
  k_zero<<<64, 256, 0, stream>>>((float*)cnt, (size_t)NN);
  k_count<<<(NE+255)/256, 256, 0, stream>>>(dst, cnt, NE);
  k_scan1<<<NBLK, 256, 0, stream>>>(cnt, cnt, btot, NN);
  k_scan2<<<1, 512, 0, stream>>>(btot, boff, NBLK);
  k_scan3<<<NBLK, 256, 0, stream>>>(cnt, boff, rowptr, NN);
  k_cursor<<<NBLK, 256, 0, stream>>>(rowptr, cursor, NN);
  k_fill<<<(NE+255)/256, 256, 0, stream>>>(dst, cursor, order, NE);
  k_gpb<<<(NB+256)/256, 256, 0, stream>>>(node_graph, gpb, NN, NB);

  // ---- weight packing ----
  const float* wihs[3] = { g0_Wih, gnn_Wih, gnn_Wih + (size_t)3*GD*GD };
  const float* whhs[3] = { g0_Whh, gnn_Whh, gnn_Whh + (size_t)3*GD*GD };
  for (int l=0;l<3;l++){
    k_pack_rz<<<1024, 256, 0, stream>>>(wihs[l], whhs[l], pGruN + l*LW);
    k_pack_b<<<256, 256, 0, stream>>>(wihs[l] + (size_t)512*GD, pGruN + l*LW + 262144, 256, GD);
    k_pack_b<<<256, 256, 0, stream>>>(whhs[l] + (size_t)512*GD, pGruN + l*LW + 327680, 256, GD);
  }
  for (int t=0;t<NT;t++){
    k_pack_b<<<768, 256, 0, stream>>>(ro_Wih + (size_t)t*3*GD*GD, pGruR + (2*t)*OW, 768, GD);
    k_pack_b<<<768, 256, 0, stream>>>(ro_Whh + (size_t)t*3*GD*GD, pGruR + (2*t+1)*OW, 768, GD);
  }
  for (int l=0;l<NL;l++)
    k_pack_b<<<256, 256, 0, stream>>>(gnn_W_pn + (size_t)l*GD*GD, pPn + l*PW, GD, GD);
  for (int t=0;t<NT;t++)
    k_pack_b<<<256, 256, 0, stream>>>(ro_W_pn + (size_t)t*GD*GD, pPn + (2+t)*PW, GD, GD);
  k_pack_b<<<256, 256, 0, stream>>>(W_et, pEt, GD, GD);

  // ---------------- GetContext ----------------
  k_node_proj<8><<<(NN+7)/8, 256, 0, stream>>>(node_feats, W_pn, FN, b_pn, 1, hv_new, NN);
  k_node_proj<8><<<(NN+7)/8, 256, 0, stream>>>(node_feats, W_pe1, FN+FE, nullptr, 0, Pbuf, NN);
  k_dot1_bf16<<<(NN+3)/4, 256, 0, stream>>>(hv_new, W_pe2, za, NN);
  k_ctx_fused<<<(NN+3)/4, 256, 0, stream>>>(Pbuf, za, order, rowptr, src, edge_feats,
                                            W_pe1, b_pe1, W_pe2, b_pe2, cwb, sdeg, NN);
  k_proj_mfma64<1><<<G64, 512, 0, stream>>>(cwb, pEt, b_et, dbuf, NN, sdeg);
  k_gru_mfma32<<<G32, 512, 0, stream>>>(dbuf, hv_new, pGruN + 0*LW, pGruN + 0*LW + 262144,
                                        pGruN + 0*LW + 327680, g0_bih, g0_bhh, hbuf, NN);

  // ---------------- GNN layers ----------------
  for (int l=0; l<NL; l++){
    k_dot2_bf16<<<(NN+3)/4, 256, 0, stream>>>(hbuf, gnn_W_pe + (size_t)l*2*GD, za, zb, NN);
    k_proj_mfma64<0><<<G64, 512, 0, stream>>>(hbuf, pPn + l*PW, gnn_b_pn + (size_t)l*GD,
                                              htmp, NN, nullptr);
    k_gnn_fused<<<(NN+3)/4, 256, 0, stream>>>(htmp, za, zb, order, rowptr, src,
                                              gnn_b_pe + l, cwb, NN);
    k_gru_mfma32<<<G32, 512, 0, stream>>>(cwb, hbuf,
                                pGruN + (1+l)*LW, pGruN + (1+l)*LW + 262144, pGruN + (1+l)*LW + 327680,
                                gnn_bih + (size_t)l*3*GD, gnn_bhh + (size_t)l*3*GD, hbuf, NN);
  }

  // ---------------- Readout ----------------
  k_segsum_sorted<<<NB, 256, 0, stream>>>(hbuf, gpb, gbuf, NB);
  for (int t=0; t<NT; t++){
    k_dotg_relu<<<(NB+3)/4, 256, 0, stream>>>(gbuf, ro_W_cl + (size_t)t*2*GD, zg, NB);
    k_dot1_bf16<<<(NN+3)/4, 256, 0, stream>>>(hbuf, ro_W_cl + (size_t)t*2*GD + GD, za, NN);
    k_proj_mfma64<0><<<G64, 512, 0, stream>>>(hbuf, pPn + (2+t)*PW, ro_b_pn + (size_t)t*GD,
                                              htmp, NN, nullptr);
    k_ro_fused<<<NB, 256, 0, stream>>>(htmp, zg, za, gpb, ro_b_cl + t, grbuf, NB);
    k_gru_mfma_f32<<<NB/16, 256, 0, stream>>>(grbuf, gbuf,
                                pGruR + (2*t)*OW, pGruR + (2*t+1)*OW,
                                ro_bih + (size_t)t*3*GD, ro_bhh + (size_t)t*3*GD, gbuf, NB);
  }
  k_layernorm<<<NB, 256, 0, stream>>>(gbuf, ln_gamma, ln_beta, outp);
}

// Round 13
// 1968.990 us; speedup vs baseline: 1.1396x; 1.1396x over previous
//
#include <hip/hip_runtime.h>

#define NN 100000
#define NE 400000
#define NB 4096
#define FN 78
#define FE 11
#define GD 256
#define NL 2
#define NT 2

typedef unsigned short u16;
typedef __attribute__((ext_vector_type(8))) short bf16x8;
typedef __attribute__((ext_vector_type(4))) float f32x4;

__device__ __forceinline__ float lrelu_(float x){ return x > 0.f ? x : 0.01f*x; }
__device__ __forceinline__ float elu_(float x){ return x > 0.f ? x : expf(x) - 1.f; }
__device__ __forceinline__ float sigm_(float x){ return 1.f/(1.f + expf(-x)); }

__device__ __forceinline__ float bf2f(u16 u){ return __uint_as_float(((unsigned)u) << 16); }
__device__ __forceinline__ u16 f2bf(float f){
  unsigned u = __float_as_uint(f);
  unsigned r = (u + 0x7fffu + ((u >> 16) & 1u)) >> 16;   // RNE
  return (u16)r;
}

__global__ void k_zero(float* p, size_t n){
  size_t i = (size_t)blockIdx.x*blockDim.x + threadIdx.x;
  size_t st = (size_t)gridDim.x*blockDim.x;
  for (; i < n; i += st) p[i] = 0.f;
}

// ---------------- CSR build (dst-sorted edge order) ----------------
__global__ void k_count(const int* __restrict__ dst, int* __restrict__ cnt, int E){
  int e = blockIdx.x*256 + threadIdx.x;
  if (e < E) atomicAdd(&cnt[dst[e]], 1);
}
__global__ void k_scan1(const int* __restrict__ cnt, int* __restrict__ part,
                        int* __restrict__ btot, int n){
  __shared__ int sd[256];
  int i = blockIdx.x*256 + threadIdx.x;
  int v = (i < n) ? cnt[i] : 0;
  sd[threadIdx.x] = v; __syncthreads();
  for (int d=1; d<256; d<<=1){
    int t = (threadIdx.x >= d) ? sd[threadIdx.x-d] : 0;
    __syncthreads();
    sd[threadIdx.x] += t;
    __syncthreads();
  }
  if (i < n) part[i] = sd[threadIdx.x];
  if (threadIdx.x == 255) btot[blockIdx.x] = sd[255];
}
__global__ void k_scan2(const int* __restrict__ btot, int* __restrict__ boff, int nb){
  __shared__ int sd[512];
  int tid = threadIdx.x;
  int v = (tid < nb) ? btot[tid] : 0;
  sd[tid] = v; __syncthreads();
  for (int d=1; d<512; d<<=1){
    int t = (tid >= d) ? sd[tid-d] : 0;
    __syncthreads();
    sd[tid] += t;
    __syncthreads();
  }
  if (tid < nb) boff[tid] = sd[tid] - v;   // exclusive
}
__global__ void k_scan3(const int* __restrict__ part, const int* __restrict__ boff,
                        int* __restrict__ rowptr, int n){
  int i = blockIdx.x*256 + threadIdx.x;
  if (i < n) rowptr[i+1] = part[i] + boff[blockIdx.x];
  if (i == 0) rowptr[0] = 0;
}
__global__ void k_cursor(const int* __restrict__ rowptr, int* __restrict__ cursor, int n){
  int i = blockIdx.x*256 + threadIdx.x;
  if (i < n) cursor[i] = rowptr[i];
}
__global__ void k_fill(const int* __restrict__ dst, int* __restrict__ cursor,
                       int* __restrict__ order, int E){
  int e = blockIdx.x*256 + threadIdx.x;
  if (e < E){
    int pos = atomicAdd(&cursor[dst[e]], 1);
    order[pos] = e;
  }
}
__global__ void k_gpb(const int* __restrict__ ng, int* __restrict__ gpb, int N, int B){
  int b = blockIdx.x*256 + threadIdx.x;
  if (b > B) return;
  int lo = 0, hi = N;
  while (lo < hi){ int mid = (lo+hi)>>1; if (ng[mid] < b) lo = mid+1; else hi = mid; }
  gpb[b] = lo;
}

// Pack W[OUT][K] f32 -> bf16 B-fragment order
__global__ void k_pack_b(const float* __restrict__ W, u16* __restrict__ Bp, int OUT, int K){
  int t = blockIdx.x*256 + threadIdx.x;
  if (t >= OUT*K) return;
  int j = t & 7;
  int l = (t >> 3) & 63;
  int rest = t >> 9;
  int nks = K >> 5;
  int ks = rest % nks, c = rest / nks;
  int col = c*16 + (l & 15);
  int k = ks*32 + (l >> 4)*8 + j;
  Bp[t] = f2bf(W[(size_t)col*K + k]);
}

// Pack W[256][ldw] (logical K padded 78 -> 96) -> bf16 B-fragment order, zeros past FN
__global__ void k_pack_b96(const float* __restrict__ W, int ldw, u16* __restrict__ Bp){
  int t = blockIdx.x*256 + threadIdx.x;
  if (t >= 256*96) return;
  int j = t & 7;
  int l = (t >> 3) & 63;
  int rest = t >> 9;
  int ks = rest % 3, c = rest / 3;
  int col = c*16 + (l & 15);
  int k = ks*32 + (l >> 4)*8 + j;
  Bp[t] = (k < FN) ? f2bf(W[(size_t)col*ldw + k]) : (u16)0;
}

// Pack r,z gates of (Wih,Whh) into one K=512 B-matrix, r/z interleaved per 16-col group
__global__ void k_pack_rz(const float* __restrict__ Wih, const float* __restrict__ Whh,
                          u16* __restrict__ Bp){
  int t = blockIdx.x*256 + threadIdx.x;   // grid covers 512*512
  int j = t & 7;
  int l = (t >> 3) & 63;
  int rest = t >> 9;
  int ks = rest & 15, c = rest >> 4;      // nks = 16
  int srcrow = (c & 1)*256 + (c >> 1)*16 + (l & 15);
  int k = ks*32 + (l >> 4)*8 + j;
  float v = (k < 256) ? Wih[(size_t)srcrow*GD + k] : Whh[(size_t)srcrow*GD + (k - 256)];
  Bp[t] = f2bf(v);
}

// ---- fused dual node projection via MFMA (K=96, zero-padded from 78) ----
// Y_A = lrelu(nf @ W_pn^T + bA) -> hv ;  Y_B = nf @ W_pe1[:, :78]^T + bB -> P
__global__ void __launch_bounds__(512)
k_np2_mfma(const float* __restrict__ nf,
           const u16* __restrict__ BpA, const float* __restrict__ bA,
           const u16* __restrict__ BpB, const float* __restrict__ bB,
           u16* __restrict__ hv, u16* __restrict__ Pb, int N){
  int tid = threadIdx.x;
  int wv = __builtin_amdgcn_readfirstlane(tid >> 6);
  int lane = tid & 63;
  int m = lane & 15, kg = lane >> 4;
  int r0 = blockIdx.x*64;
  f32x4 accA[2][4], accB[2][4];
  #pragma unroll
  for (int t=0;t<2;t++)
    #pragma unroll
    for (int rt=0;rt<4;rt++){ accA[t][rt] = (f32x4)(0.f); accB[t][rt] = (f32x4)(0.f); }
  #pragma unroll
  for (int ks=0; ks<3; ks++){
    int koff = ks*32 + kg*8;
    bf16x8 a[4];
    #pragma unroll
    for (int rt=0; rt<4; rt++){
      int row = r0 + rt*16 + m;
      if (row > N-1) row = N-1;
      const float* base = nf + (size_t)row*FN;
      #pragma unroll
      for (int q=0;q<8;q++){
        int k = koff + q;
        a[rt][q] = (short)((k < FN) ? f2bf(base[k]) : (u16)0);
      }
    }
    #pragma unroll
    for (int t=0;t<2;t++){
      int c = wv*2 + t;
      bf16x8 bva = *(const bf16x8*)&BpA[(size_t)((c*3 + ks)*64 + lane)*8];
      bf16x8 bvb = *(const bf16x8*)&BpB[(size_t)((c*3 + ks)*64 + lane)*8];
      #pragma unroll
      for (int rt=0; rt<4; rt++){
        accA[t][rt] = __builtin_amdgcn_mfma_f32_16x16x32_bf16(a[rt], bva, accA[t][rt], 0, 0, 0);
        accB[t][rt] = __builtin_amdgcn_mfma_f32_16x16x32_bf16(a[rt], bvb, accB[t][rt], 0, 0, 0);
      }
    }
  }
  #pragma unroll
  for (int t=0;t<2;t++){
    int col = wv*32 + t*16 + m;
    float ba = bA[col], bb = bB[col];
    #pragma unroll
    for (int rt=0; rt<4; rt++){
      #pragma unroll
      for (int i=0;i<4;i++){
        int row = r0 + rt*16 + kg*4 + i;
        if (row < N){
          hv[(size_t)row*GD + col] = f2bf(lrelu_(accA[t][rt][i] + ba));
          Pb[(size_t)row*GD + col] = f2bf(accB[t][rt][i] + bb);
        }
      }
    }
  }
}

// ---- per-node dot kernels ----
__global__ void k_dot2_bf16(const u16* __restrict__ rows, const float* __restrict__ wv,
                            float* __restrict__ za, float* __restrict__ zb, int N){
  int wav = threadIdx.x >> 6, lane = threadIdx.x & 63;
  int i = blockIdx.x*4 + wav;
  if (i >= N) return;
  int c0 = lane*4;
  ushort4 r4 = *(const ushort4*)&rows[(size_t)i*GD + c0];
  float4 wa = *(const float4*)&wv[c0];
  float4 wb = *(const float4*)&wv[GD + c0];
  float v0 = bf2f(r4.x), v1 = bf2f(r4.y), v2 = bf2f(r4.z), v3 = bf2f(r4.w);
  float va = v0*wa.x + v1*wa.y + v2*wa.z + v3*wa.w;
  float vb = v0*wb.x + v1*wb.y + v2*wb.z + v3*wb.w;
  #pragma unroll
  for (int off=32; off; off>>=1){ va += __shfl_down(va, off); vb += __shfl_down(vb, off); }
  if (lane == 0){ za[i] = va; zb[i] = vb; }
}

__global__ void k_dot1_bf16(const u16* __restrict__ rows, const float* __restrict__ wv,
                            float* __restrict__ z, int N){
  int wav = threadIdx.x >> 6, lane = threadIdx.x & 63;
  int i = blockIdx.x*4 + wav;
  if (i >= N) return;
  int c0 = lane*4;
  ushort4 r4 = *(const ushort4*)&rows[(size_t)i*GD + c0];
  float4 wa = *(const float4*)&wv[c0];
  float va = bf2f(r4.x)*wa.x + bf2f(r4.y)*wa.y + bf2f(r4.z)*wa.z + bf2f(r4.w)*wa.w;
  #pragma unroll
  for (int off=32; off; off>>=1) va += __shfl_down(va, off);
  if (lane == 0) z[i] = va;
}

__global__ void k_dotg_relu(const float* __restrict__ g, const float* __restrict__ wv,
                            float* __restrict__ zg, int B){
  int wav = threadIdx.x >> 6, lane = threadIdx.x & 63;
  int i = blockIdx.x*4 + wav;
  if (i >= B) return;
  int c0 = lane*4;
  float4 gv = *(const float4*)&g[(size_t)i*GD + c0];
  float4 wa = *(const float4*)&wv[c0];
  float va = fmaxf(gv.x,0.f)*wa.x + fmaxf(gv.y,0.f)*wa.y + fmaxf(gv.z,0.f)*wa.z + fmaxf(gv.w,0.f)*wa.w;
  #pragma unroll
  for (int off=32; off; off>>=1) va += __shfl_down(va, off);
  if (lane == 0) zg[i] = va;
}

// ---- GetContext fused (round-10 form: no prefetch, 48 VGPR, occupancy ~44%) ----
__global__ void __launch_bounds__(256)
k_ctx_fused(const u16* __restrict__ P, const float* __restrict__ za,
            const int* __restrict__ order, const int* __restrict__ rowptr,
            const int* __restrict__ src, const float* __restrict__ ef,
            const float* __restrict__ Wpe1, const float* __restrict__ bpe1,
            const float* __restrict__ Wpe2, const float* __restrict__ bpe2,
            u16* __restrict__ wc, float* __restrict__ sdeg, int N){
  int wv = threadIdx.x >> 6, lane = threadIdx.x & 63;
  int d = blockIdx.x*4 + wv;
  if (d >= N) return;
  int j0 = rowptr[d], j1 = rowptr[d+1];
  int c0 = lane*4;
  float wb0 = Wpe2[GD+c0], wb1 = Wpe2[GD+c0+1], wb2 = Wpe2[GD+c0+2], wb3 = Wpe2[GD+c0+3];
  float bp0 = bpe1[c0], bp1 = bpe1[c0+1], bp2 = bpe1[c0+2], bp3 = bpe1[c0+3];
  float wk0[FE], wk1[FE], wk2[FE], wk3[FE];
  #pragma unroll
  for (int k=0;k<FE;k++){
    wk0[k] = Wpe1[(size_t)(c0+0)*(FN+FE) + FN + k];
    wk1[k] = Wpe1[(size_t)(c0+1)*(FN+FE) + FN + k];
    wk2[k] = Wpe1[(size_t)(c0+2)*(FN+FE) + FN + k];
    wk3[k] = Wpe1[(size_t)(c0+3)*(FN+FE) + FN + k];
  }
  float zad = za[d] + bpe2[0];
  float m = -1e30f, s = 0.f;
  float a0=0.f, a1=0.f, a2=0.f, a3=0.f;
  for (int j=j0; j<j1; j++){
    int e = order[j];
    int sn = src[e];
    ushort4 p4 = *(const ushort4*)&P[(size_t)sn*GD + c0];
    const float* efp = &ef[(size_t)e*FE];
    float efv[FE];
    #pragma unroll
    for (int k=0;k<FE;k++) efv[k] = efp[k];
    float h0 = bf2f(p4.x)+bp0, h1 = bf2f(p4.y)+bp1, h2 = bf2f(p4.z)+bp2, h3 = bf2f(p4.w)+bp3;
    #pragma unroll
    for (int k=0;k<FE;k++){
      h0 += wk0[k]*efv[k]; h1 += wk1[k]*efv[k]; h2 += wk2[k]*efv[k]; h3 += wk3[k]*efv[k];
    }
    h0 = lrelu_(h0); h1 = lrelu_(h1); h2 = lrelu_(h2); h3 = lrelu_(h3);
    float part = h0*wb0 + h1*wb1 + h2*wb2 + h3*wb3;
    #pragma unroll
    for (int off=32; off; off>>=1) part += __shfl_down(part, off);
    float l = lrelu_(part + zad);
    l = __shfl(l, 0);
    float mn = fmaxf(m, l);
    float sc = __expf(m - mn);
    float p  = __expf(l - mn);
    s = s*sc + p;
    a0 = a0*sc + p*h0; a1 = a1*sc + p*h1; a2 = a2*sc + p*h2; a3 = a3*sc + p*h3;
    m = mn;
  }
  float inv = (j1 > j0) ? 1.f/s : 0.f;
  ushort4 o;
  o.x = f2bf(a0*inv); o.y = f2bf(a1*inv); o.z = f2bf(a2*inv); o.w = f2bf(a3*inv);
  *(ushort4*)&wc[(size_t)d*GD + c0] = o;
  if (lane == 0) sdeg[d] = (j1 > j0) ? 1.f : 0.f;
}

// ---- GNN layer fused, TWO-PASS (logits scalar-only -> no rescale chain) ----
__global__ void __launch_bounds__(256)
k_gnn_fused(const u16* __restrict__ hv, const float* __restrict__ za, const float* __restrict__ zb,
            const int* __restrict__ order, const int* __restrict__ rowptr,
            const int* __restrict__ src, const float* __restrict__ bias,
            u16* __restrict__ cw, int N){
  int wv = threadIdx.x >> 6, lane = threadIdx.x & 63;
  int d = blockIdx.x*4 + wv;
  if (d >= N) return;
  int j0 = rowptr[d], j1 = rowptr[d+1];
  int c0 = lane*4;
  float zad = za[d] + bias[0];
  float M = -1e30f;
  for (int j=j0; j<j1; j++){
    int sn = src[order[j]];
    M = fmaxf(M, lrelu_(zad + zb[sn]));
  }
  float s = 0.f;
  float a0=0.f, a1=0.f, a2=0.f, a3=0.f;
  for (int j=j0; j<j1; j++){
    int e = order[j];
    int sn = src[e];
    float p = __expf(lrelu_(zad + zb[sn]) - M);
    ushort4 r4 = *(const ushort4*)&hv[(size_t)sn*GD + c0];
    s += p;
    a0 += p*bf2f(r4.x);
    a1 += p*bf2f(r4.y);
    a2 += p*bf2f(r4.z);
    a3 += p*bf2f(r4.w);
  }
  float inv = (j1 > j0) ? 1.f/s : 0.f;
  ushort4 o;
  o.x = f2bf(elu_(a0*inv)); o.y = f2bf(elu_(a1*inv));
  o.z = f2bf(elu_(a2*inv)); o.w = f2bf(elu_(a3*inv));
  *(ushort4*)&cw[(size_t)d*GD + c0] = o;
}

// ---- readout fused ----
__global__ void __launch_bounds__(256)
k_ro_fused(const u16* __restrict__ hv, const float* __restrict__ zg, const float* __restrict__ zh,
           const int* __restrict__ gpb, const float* __restrict__ bias,
           float* __restrict__ gr, int B){
  int b = blockIdx.x, tid = threadIdx.x;
  int i0 = gpb[b], i1 = gpb[b+1];
  float zgb = zg[b] + bias[0];
  __shared__ float red[256];
  float lm = -1e30f;
  for (int i = i0 + tid; i < i1; i += 256) lm = fmaxf(lm, lrelu_(zgb + zh[i]));
  red[tid] = lm; __syncthreads();
  for (int d2=128; d2; d2>>=1){ if (tid < d2) red[tid] = fmaxf(red[tid], red[tid+d2]); __syncthreads(); }
  float M = red[0]; __syncthreads();
  float ls = 0.f;
  for (int i = i0 + tid; i < i1; i += 256) ls += __expf(lrelu_(zgb + zh[i]) - M);
  red[tid] = ls; __syncthreads();
  for (int d2=128; d2; d2>>=1){ if (tid < d2) red[tid] += red[tid+d2]; __syncthreads(); }
  float S = red[0];
  float acc = 0.f;
  for (int i = i0; i < i1; i++){
    float p = __expf(lrelu_(zgb + zh[i]) - M);
    acc += p * bf2f(hv[(size_t)i*GD + tid]);
  }
  gr[(size_t)b*GD + tid] = (i1 > i0) ? acc/S : 0.f;
}

__global__ void k_segsum_sorted(const u16* __restrict__ h, const int* __restrict__ gpb,
                                float* __restrict__ g, int B){
  int b = blockIdx.x, tid = threadIdx.x;
  int i0 = gpb[b], i1 = gpb[b+1];
  float acc = 0.f;
  for (int i = i0; i < i1; i++) acc += bf2f(h[(size_t)i*GD + tid]);
  g[(size_t)b*GD + tid] = acc;
}

// ---- 32-row MFMA GRU with fused r/z gates (K=512 concat) ----
__global__ void __launch_bounds__(512)
k_gru_mfma32(const u16* __restrict__ x, const u16* __restrict__ hprev,
             const u16* __restrict__ rzp, const u16* __restrict__ nip, const u16* __restrict__ nhp,
             const float* __restrict__ bih, const float* __restrict__ bhh,
             u16* __restrict__ hout, int R){
  int tid = threadIdx.x;
  int wv = __builtin_amdgcn_readfirstlane(tid >> 6);
  int lane = tid & 63;
  int m = lane & 15, kg = lane >> 4;
  int r0 = blockIdx.x*32;   // R must be a multiple of 32 (100000 = 3125*32)

  f32x4 arz[2][4], ani[2][2], anh[2][2];
  #pragma unroll
  for (int rt=0;rt<2;rt++){
    #pragma unroll
    for (int t=0;t<4;t++) arz[rt][t] = (f32x4)(0.f);
    #pragma unroll
    for (int t=0;t<2;t++){ ani[rt][t] = (f32x4)(0.f); anh[rt][t] = (f32x4)(0.f); }
  }

  #pragma unroll
  for (int ks=0; ks<8; ks++){
    int koff = ks*32 + kg*8;
    bf16x8 ax[2], ah[2];
    #pragma unroll
    for (int rt=0; rt<2; rt++){
      int row = r0 + rt*16 + m;
      ax[rt] = *(const bf16x8*)&x[(size_t)row*GD + koff];
      ah[rt] = *(const bf16x8*)&hprev[(size_t)row*GD + koff];
    }
    #pragma unroll
    for (int t=0;t<4;t++){
      int c = wv*4 + t;
      bf16x8 bx = *(const bf16x8*)&rzp[(size_t)((c*16 + ks    )*64 + lane)*8];
      bf16x8 bh = *(const bf16x8*)&rzp[(size_t)((c*16 + ks + 8)*64 + lane)*8];
      #pragma unroll
      for (int rt=0; rt<2; rt++){
        arz[rt][t] = __builtin_amdgcn_mfma_f32_16x16x32_bf16(ax[rt], bx, arz[rt][t], 0, 0, 0);
        arz[rt][t] = __builtin_amdgcn_mfma_f32_16x16x32_bf16(ah[rt], bh, arz[rt][t], 0, 0, 0);
      }
    }
    #pragma unroll
    for (int t=0;t<2;t++){
      int c = wv*2 + t;
      bf16x8 bi = *(const bf16x8*)&nip[(size_t)((c*8 + ks)*64 + lane)*8];
      bf16x8 bh = *(const bf16x8*)&nhp[(size_t)((c*8 + ks)*64 + lane)*8];
      #pragma unroll
      for (int rt=0; rt<2; rt++){
        ani[rt][t] = __builtin_amdgcn_mfma_f32_16x16x32_bf16(ax[rt], bi, ani[rt][t], 0, 0, 0);
        anh[rt][t] = __builtin_amdgcn_mfma_f32_16x16x32_bf16(ah[rt], bh, anh[rt][t], 0, 0, 0);
      }
    }
  }

  #pragma unroll
  for (int g=0; g<2; g++){
    int ch = (wv*2 + g)*16 + m;
    float brz_r = bih[ch] + bhh[ch];
    float brz_z = bih[ch+GD] + bhh[ch+GD];
    float bin   = bih[ch+2*GD];
    float bhn   = bhh[ch+2*GD];
    #pragma unroll
    for (int rt=0; rt<2; rt++){
      #pragma unroll
      for (int i=0;i<4;i++){
        int row = r0 + rt*16 + kg*4 + i;
        float rr = sigm_(arz[rt][2*g  ][i] + brz_r);
        float zz = sigm_(arz[rt][2*g+1][i] + brz_z);
        float nn = tanhf(ani[rt][g][i] + bin + rr*(anh[rt][g][i] + bhn));
        float hp = bf2f(hprev[(size_t)row*GD + ch]);
        float o = (1.f - zz)*nn + zz*hp;
        hout[(size_t)row*GD + ch] = f2bf(fmaxf(o, 0.f));
      }
    }
  }
}

// ---- 64-row MFMA projection: Y = X@W^T + b, optional mask+elu epilogue ----
template<int DO_ELU>
__global__ void __launch_bounds__(512)
k_proj_mfma64(const u16* __restrict__ X, const u16* __restrict__ Wp,
              const float* __restrict__ b, u16* __restrict__ Y, int R,
              const float* __restrict__ mask){
  int tid = threadIdx.x;
  int wv = __builtin_amdgcn_readfirstlane(tid >> 6);
  int lane = tid & 63;
  int m = lane & 15, kg = lane >> 4;
  int r0 = blockIdx.x*64;
  f32x4 acc[2][4];
  #pragma unroll
  for (int t=0;t<2;t++)
    #pragma unroll
    for (int rt=0;rt<4;rt++) acc[t][rt] = (f32x4)(0.f);
  #pragma unroll
  for (int ks=0; ks<8; ks++){
    int koff = ks*32 + kg*8;
    bf16x8 a[4];
    #pragma unroll
    for (int rt=0; rt<4; rt++){
      int row = r0 + rt*16 + m;
      if (row > R-1) row = R-1;
      a[rt] = *(const bf16x8*)&X[(size_t)row*GD + koff];
    }
    #pragma unroll
    for (int t=0;t<2;t++){
      int c = wv*2 + t;
      bf16x8 bv = *(const bf16x8*)&Wp[(size_t)((c*8 + ks)*64 + lane)*8];
      #pragma unroll
      for (int rt=0; rt<4; rt++)
        acc[t][rt] = __builtin_amdgcn_mfma_f32_16x16x32_bf16(a[rt], bv, acc[t][rt], 0, 0, 0);
    }
  }
  #pragma unroll
  for (int t=0;t<2;t++){
    int col = wv*32 + t*16 + m;
    float bb = b[col];
    #pragma unroll
    for (int rt=0; rt<4; rt++){
      #pragma unroll
      for (int i=0;i<4;i++){
        int row = r0 + rt*16 + kg*4 + i;
        if (row < R){
          float v = acc[t][rt][i] + bb;
          if (DO_ELU){
            float mk = (mask[row] > 0.f) ? 1.f : 0.f;
            v = elu_(v*mk);
          }
          Y[(size_t)row*GD + col] = f2bf(v);
        }
      }
    }
  }
}

// ---- 16-row MFMA GRU for readout (f32 in/out, elu applied here) ----
__global__ void __launch_bounds__(256)
k_gru_mfma_f32(const float* __restrict__ x, const float* __restrict__ hprev,
               const u16* __restrict__ Wihp, const u16* __restrict__ Whhp,
               const float* __restrict__ bih, const float* __restrict__ bhh,
               float* __restrict__ hout, int R){
  int tid = threadIdx.x;
  int wave = __builtin_amdgcn_readfirstlane(tid >> 6);
  int lane = tid & 63;
  int m = lane & 15, kg = lane >> 4;
  int r0 = blockIdx.x*16;

  f32x4 agi[3][4], agh[3][4];
  #pragma unroll
  for (int g=0;g<3;g++)
    #pragma unroll
    for (int t=0;t<4;t++){ agi[g][t] = (f32x4)(0.f); agh[g][t] = (f32x4)(0.f); }

  #pragma unroll
  for (int ks=0; ks<8; ks++){
    int koff = ks*32 + kg*8;
    const float* xp = x + (size_t)(r0 + m)*GD + koff;
    float4 x0 = *(const float4*)xp;
    float4 x1 = *(const float4*)(xp+4);
    bf16x8 ax;
    ax[0]=(short)f2bf(elu_(x0.x)); ax[1]=(short)f2bf(elu_(x0.y));
    ax[2]=(short)f2bf(elu_(x0.z)); ax[3]=(short)f2bf(elu_(x0.w));
    ax[4]=(short)f2bf(elu_(x1.x)); ax[5]=(short)f2bf(elu_(x1.y));
    ax[6]=(short)f2bf(elu_(x1.z)); ax[7]=(short)f2bf(elu_(x1.w));
    const float* hr = hprev + (size_t)(r0 + m)*GD + koff;
    float4 h0 = *(const float4*)hr;
    float4 h1 = *(const float4*)(hr+4);
    bf16x8 ah;
    ah[0]=(short)f2bf(h0.x); ah[1]=(short)f2bf(h0.y); ah[2]=(short)f2bf(h0.z); ah[3]=(short)f2bf(h0.w);
    ah[4]=(short)f2bf(h1.x); ah[5]=(short)f2bf(h1.y); ah[6]=(short)f2bf(h1.z); ah[7]=(short)f2bf(h1.w);
    #pragma unroll
    for (int g=0;g<3;g++){
      #pragma unroll
      for (int t=0;t<4;t++){
        int c = g*16 + wave*4 + t;
        bf16x8 bi = *(const bf16x8*)&Wihp[(size_t)((c*8 + ks)*64 + lane)*8];
        bf16x8 bh = *(const bf16x8*)&Whhp[(size_t)((c*8 + ks)*64 + lane)*8];
        agi[g][t] = __builtin_amdgcn_mfma_f32_16x16x32_bf16(ax, bi, agi[g][t], 0, 0, 0);
        agh[g][t] = __builtin_amdgcn_mfma_f32_16x16x32_bf16(ah, bh, agh[g][t], 0, 0, 0);
      }
    }
  }
  #pragma unroll
  for (int t=0;t<4;t++){
    int col = wave*64 + t*16 + m;
    float bir = bih[col],      bhr = bhh[col];
    float biz = bih[col+GD],   bhz = bhh[col+GD];
    float bin = bih[col+2*GD], bhn = bhh[col+2*GD];
    #pragma unroll
    for (int i=0;i<4;i++){
      int row = r0 + kg*4 + i;
      float rr = sigm_(agi[0][t][i] + bir + agh[0][t][i] + bhr);
      float zz = sigm_(agi[1][t][i] + biz + agh[1][t][i] + bhz);
      float nn = tanhf(agi[2][t][i] + bin + rr*(agh[2][t][i] + bhn));
      float hp = hprev[(size_t)row*GD + col];
      float o = (1.f - zz)*nn + zz*hp;
      hout[(size_t)row*GD + col] = fmaxf(o, 0.f);
    }
  }
}

__global__ void k_layernorm(const float* __restrict__ gb, const float* __restrict__ gamma,
                            const float* __restrict__ beta, float* __restrict__ outb){
  int r = blockIdx.x, j = threadIdx.x;
  float v = gb[(size_t)r*GD + j];
  float s1 = v, s2 = v*v;
  #pragma unroll
  for (int off=32; off; off>>=1){ s1 += __shfl_down(s1, off); s2 += __shfl_down(s2, off); }
  __shared__ float r1[4], r2[4];
  int wv = j >> 6, lane = j & 63;
  if (lane == 0){ r1[wv] = s1; r2[wv] = s2; }
  __syncthreads();
  float S1 = r1[0]+r1[1]+r1[2]+r1[3];
  float S2 = r2[0]+r2[1]+r2[2]+r2[3];
  float mu = S1/(float)GD;
  float var = fmaxf(S2/(float)GD - mu*mu, 0.f);
  outb[(size_t)r*GD + j] = (v - mu)/sqrtf(var + 1e-5f)*gamma[j] + beta[j];
}

extern "C" void kernel_launch(void* const* d_in, const int* in_sizes, int n_in,
                              void* d_out, int out_size, void* d_ws, size_t ws_size,
                              hipStream_t stream){
  const float* node_feats = (const float*)d_in[0];
  const float* edge_feats = (const float*)d_in[1];
  const int*   src        = (const int*)d_in[2];
  const int*   dst        = (const int*)d_in[3];
  const int*   node_graph = (const int*)d_in[4];
  const float* W_pn   = (const float*)d_in[5];
  const float* b_pn   = (const float*)d_in[6];
  const float* W_pe1  = (const float*)d_in[7];
  const float* b_pe1  = (const float*)d_in[8];
  const float* W_pe2  = (const float*)d_in[9];
  const float* b_pe2  = (const float*)d_in[10];
  const float* W_et   = (const float*)d_in[11];
  const float* b_et   = (const float*)d_in[12];
  const float* g0_Wih = (const float*)d_in[13];
  const float* g0_Whh = (const float*)d_in[14];
  const float* g0_bih = (const float*)d_in[15];
  const float* g0_bhh = (const float*)d_in[16];
  const float* gnn_W_pe = (const float*)d_in[17];
  const float* gnn_b_pe = (const float*)d_in[18];
  const float* gnn_W_pn = (const float*)d_in[19];
  const float* gnn_b_pn = (const float*)d_in[20];
  const float* gnn_Wih  = (const float*)d_in[21];
  const float* gnn_Whh  = (const float*)d_in[22];
  const float* gnn_bih  = (const float*)d_in[23];
  const float* gnn_bhh  = (const float*)d_in[24];
  const float* ro_W_cl = (const float*)d_in[25];
  const float* ro_b_cl = (const float*)d_in[26];
  const float* ro_W_pn = (const float*)d_in[27];
  const float* ro_b_pn = (const float*)d_in[28];
  const float* ro_Wih  = (const float*)d_in[29];
  const float* ro_Whh  = (const float*)d_in[30];
  const float* ro_bih  = (const float*)d_in[31];
  const float* ro_bhh  = (const float*)d_in[32];
  const float* ln_gamma = (const float*)d_in[33];
  const float* ln_beta  = (const float*)d_in[34];
  float* outp = (float*)d_out;

  const int NBLK = (NN + 255)/256;

  // ---- workspace layout ----
  char* w = (char*)d_ws;
  size_t need = 0;
  float* gbuf  = (float*)(w + need); need += (size_t)NB*GD*4;
  float* grbuf = (float*)(w + need); need += (size_t)NB*GD*4;
  float* za    = (float*)(w + need); need += (size_t)NN*4;
  float* zb    = (float*)(w + need); need += (size_t)NN*4;
  float* zg    = (float*)(w + need); need += (size_t)NB*4;
  float* sdeg  = (float*)(w + need); need += (size_t)NN*4;
  int*   cnt    = (int*)(w + need); need += (size_t)NN*4;
  int*   rowptr = (int*)(w + need); need += (size_t)(NN+1)*4;
  int*   cursor = (int*)(w + need); need += (size_t)NN*4;
  int*   order  = (int*)(w + need); need += (size_t)NE*4;
  int*   gpb    = (int*)(w + need); need += (size_t)(NB+1)*4;
  int*   btot   = (int*)(w + need); need += (size_t)512*4;
  int*   boff   = (int*)(w + need); need += (size_t)512*4;
  u16*   hbuf = (u16*)(w + need); need += (size_t)NN*GD*2;
  u16*   htmp = (u16*)(w + need); need += (size_t)NN*GD*2;
  u16*   cwb  = (u16*)(w + need); need += (size_t)NN*GD*2;
  u16*   dbuf = (u16*)(w + need); need += (size_t)NN*GD*2;
  u16* pGruN = (u16*)(w + need); need += (size_t)3*393216*2;  // g0, gnn0, gnn1 (rz+ni+nh)
  u16* pGruR = (u16*)(w + need); need += (size_t)4*196608*2;  // ro Wih/Whh x2 (old format)
  u16* pPn  = (u16*)(w + need); need += (size_t)4*GD*GD*2;
  u16* pEt  = (u16*)(w + need); need += (size_t)GD*GD*2;
  u16* pNp  = (u16*)(w + need); need += (size_t)2*256*96*2;   // W_pn + W_pe1[:, :78] (K=96)
  if (ws_size < need) return;
  u16* Pbuf   = hbuf;
  u16* hv_new = htmp;

  const size_t LW = 393216;          // per-layer new-format pack (rz 262144 + ni 65536 + nh 65536)
  const size_t OW = 196608;          // old-format 768x256 pack
  const size_t PW = (size_t)GD*GD;
  const size_t NPW = (size_t)256*96;
  const int G64 = (NN + 63)/64;
  const int G32 = NN/32;             // 100000/32 = 3125 exact

  // ---- CSR build + graph rowptr ----
  k_zero<<<64, 256, 0, stream>>>((float*)cnt, (size_t)NN);
  k_count<<<(NE+255)/256, 256, 0, stream>>>(dst, cnt, NE);
  k_scan1<<<NBLK, 256, 0, stream>>>(cnt, cnt, btot, NN);
  k_scan2<<<1, 512, 0, stream>>>(btot, boff, NBLK);
  k_scan3<<<NBLK, 256, 0, stream>>>(cnt, boff, rowptr, NN);
  k_cursor<<<NBLK, 256, 0, stream>>>(rowptr, cursor, NN);
  k_fill<<<(NE+255)/256, 256, 0, stream>>>(dst, cursor, order, NE);
  k_gpb<<<(NB+256)/256, 256, 0, stream>>>(node_graph, gpb, NN, NB);

  // ---- weight packing ----
  const float* wihs[3] = { g0_Wih, gnn_Wih, gnn_Wih + (size_t)3*GD*GD };
  const float* whhs[3] = { g0_Whh, gnn_Whh, gnn_Whh + (size_t)3*GD*GD };
  for (int l=0;l<3;l++){
    k_pack_rz<<<1024, 256, 0, stream>>>(wihs[l], whhs[l], pGruN + l*LW);
    k_pack_b<<<256, 256, 0, stream>>>(wihs[l] + (size_t)512*GD, pGruN + l*LW + 262144, 256, GD);
    k_pack_b<<<256, 256, 0, stream>>>(whhs[l] + (size_t)512*GD, pGruN + l*LW + 327680, 256, GD);
  }
  for (int t=0;t<NT;t++){
    k_pack_b<<<768, 256, 0, stream>>>(ro_Wih + (size_t)t*3*GD*GD, pGruR + (2*t)*OW, 768, GD);
    k_pack_b<<<768, 256, 0, stream>>>(ro_Whh + (size_t)t*3*GD*GD, pGruR + (2*t+1)*OW, 768, GD);
  }
  for (int l=0;l<NL;l++)
    k_pack_b<<<256, 256, 0, stream>>>(gnn_W_pn + (size_t)l*GD*GD, pPn + l*PW, GD, GD);
  for (int t=0;t<NT;t++)
    k_pack_b<<<256, 256, 0, stream>>>(ro_W_pn + (size_t)t*GD*GD, pPn + (2+t)*PW, GD, GD);
  k_pack_b<<<256, 256, 0, stream>>>(W_et, pEt, GD, GD);
  k_pack_b96<<<96, 256, 0, stream>>>(W_pn, FN, pNp);
  k_pack_b96<<<96, 256, 0, stream>>>(W_pe1, FN+FE, pNp + NPW);

  // ---------------- GetContext ----------------
  k_np2_mfma<<<G64, 512, 0, stream>>>(node_feats, pNp, b_pn, pNp + NPW, b_pe1,
                                      hv_new, Pbuf, NN);
  k_dot1_bf16<<<(NN+3)/4, 256, 0, stream>>>(hv_new, W_pe2, za, NN);
  k_ctx_fused<<<(NN+3)/4, 256, 0, stream>>>(Pbuf, za, order, rowptr, src, edge_feats,
                                            W_pe1, b_pe1, W_pe2, b_pe2, cwb, sdeg, NN);
  k_proj_mfma64<1><<<G64, 512, 0, stream>>>(cwb, pEt, b_et, dbuf, NN, sdeg);
  k_gru_mfma32<<<G32, 512, 0, stream>>>(dbuf, hv_new, pGruN + 0*LW, pGruN + 0*LW + 262144,
                                        pGruN + 0*LW + 327680, g0_bih, g0_bhh, hbuf, NN);

  // ---------------- GNN layers ----------------
  for (int l=0; l<NL; l++){
    k_dot2_bf16<<<(NN+3)/4, 256, 0, stream>>>(hbuf, gnn_W_pe + (size_t)l*2*GD, za, zb, NN);
    k_proj_mfma64<0><<<G64, 512, 0, stream>>>(hbuf, pPn + l*PW, gnn_b_pn + (size_t)l*GD,
                                              htmp, NN, nullptr);
    k_gnn_fused<<<(NN+3)/4, 256, 0, stream>>>(htmp, za, zb, order, rowptr, src,
                                              gnn_b_pe + l, cwb, NN);
    k_gru_mfma32<<<G32, 512, 0, stream>>>(cwb, hbuf,
                                pGruN + (1+l)*LW, pGruN + (1+l)*LW + 262144, pGruN + (1+l)*LW + 327680,
                                gnn_bih + (size_t)l*3*GD, gnn_bhh + (size_t)l*3*GD, hbuf, NN);
  }

  // ---------------- Readout ----------------
  k_segsum_sorted<<<NB, 256, 0, stream>>>(hbuf, gpb, gbuf, NB);
  for (int t=0; t<NT; t++){
    k_dotg_relu<<<(NB+3)/4, 256, 0, stream>>>(gbuf, ro_W_cl + (size_t)t*2*GD, zg, NB);
    k_dot1_bf16<<<(NN+3)/4, 256, 0, stream>>>(hbuf, ro_W_cl + (size_t)t*2*GD + GD, za, NN);
    k_proj_mfma64<0><<<G64, 512, 0, stream>>>(hbuf, pPn + (2+t)*PW, ro_b_pn + (size_t)t*GD,
                                              htmp, NN, nullptr);
    k_ro_fused<<<NB, 256, 0, stream>>>(htmp, zg, za, gpb, ro_b_cl + t, grbuf, NB);
    k_gru_mfma_f32<<<NB/16, 256, 0, stream>>>(grbuf, gbuf,
                                pGruR + (2*t)*OW, pGruR + (2*t+1)*OW,
                                ro_bih + (size_t)t*3*GD, ro_bhh + (size_t)t*3*GD, gbuf, NB);
  }
  k_layernorm<<<NB, 256, 0, stream>>>(gbuf, ln_gamma, ln_beta, outp);
}

// Round 14
// 1966.106 us; speedup vs baseline: 1.1412x; 1.0015x over previous
//
#include <hip/hip_runtime.h>

#define NN 100000
#define NE 400000
#define NB 4096
#define FN 78
#define FE 11
#define GD 256
#define NL 2
#define NT 2

typedef unsigned short u16;
typedef __attribute__((ext_vector_type(8))) short bf16x8;
typedef __attribute__((ext_vector_type(4))) float f32x4;

__device__ __forceinline__ float lrelu_(float x){ return x > 0.f ? x : 0.01f*x; }
__device__ __forceinline__ float elu_(float x){ return x > 0.f ? x : expf(x) - 1.f; }
__device__ __forceinline__ float sigm_(float x){ return 1.f/(1.f + expf(-x)); }

__device__ __forceinline__ float bf2f(u16 u){ return __uint_as_float(((unsigned)u) << 16); }
__device__ __forceinline__ u16 f2bf(float f){
  unsigned u = __float_as_uint(f);
  unsigned r = (u + 0x7fffu + ((u >> 16) & 1u)) >> 16;   // RNE
  return (u16)r;
}

__global__ void k_zero(float* p, size_t n){
  size_t i = (size_t)blockIdx.x*blockDim.x + threadIdx.x;
  size_t st = (size_t)gridDim.x*blockDim.x;
  for (; i < n; i += st) p[i] = 0.f;
}

// ---------------- CSR build (dst-sorted edge order) ----------------
__global__ void k_count(const int* __restrict__ dst, int* __restrict__ cnt, int E){
  int e = blockIdx.x*256 + threadIdx.x;
  if (e < E) atomicAdd(&cnt[dst[e]], 1);
}
__global__ void k_scan1(const int* __restrict__ cnt, int* __restrict__ part,
                        int* __restrict__ btot, int n){
  __shared__ int sd[256];
  int i = blockIdx.x*256 + threadIdx.x;
  int v = (i < n) ? cnt[i] : 0;
  sd[threadIdx.x] = v; __syncthreads();
  for (int d=1; d<256; d<<=1){
    int t = (threadIdx.x >= d) ? sd[threadIdx.x-d] : 0;
    __syncthreads();
    sd[threadIdx.x] += t;
    __syncthreads();
  }
  if (i < n) part[i] = sd[threadIdx.x];
  if (threadIdx.x == 255) btot[blockIdx.x] = sd[255];
}
__global__ void k_scan2(const int* __restrict__ btot, int* __restrict__ boff, int nb){
  __shared__ int sd[512];
  int tid = threadIdx.x;
  int v = (tid < nb) ? btot[tid] : 0;
  sd[tid] = v; __syncthreads();
  for (int d=1; d<512; d<<=1){
    int t = (tid >= d) ? sd[tid-d] : 0;
    __syncthreads();
    sd[tid] += t;
    __syncthreads();
  }
  if (tid < nb) boff[tid] = sd[tid] - v;   // exclusive
}
__global__ void k_scan3(const int* __restrict__ part, const int* __restrict__ boff,
                        int* __restrict__ rowptr, int n){
  int i = blockIdx.x*256 + threadIdx.x;
  if (i < n) rowptr[i+1] = part[i] + boff[blockIdx.x];
  if (i == 0) rowptr[0] = 0;
}
__global__ void k_cursor(const int* __restrict__ rowptr, int* __restrict__ cursor, int n){
  int i = blockIdx.x*256 + threadIdx.x;
  if (i < n) cursor[i] = rowptr[i];
}
__global__ void k_fill(const int* __restrict__ dst, int* __restrict__ cursor,
                       int* __restrict__ order, int E){
  int e = blockIdx.x*256 + threadIdx.x;
  if (e < E){
    int pos = atomicAdd(&cursor[dst[e]], 1);
    order[pos] = e;
  }
}
__global__ void k_gpb(const int* __restrict__ ng, int* __restrict__ gpb, int N, int B){
  int b = blockIdx.x*256 + threadIdx.x;
  if (b > B) return;
  int lo = 0, hi = N;
  while (lo < hi){ int mid = (lo+hi)>>1; if (ng[mid] < b) lo = mid+1; else hi = mid; }
  gpb[b] = lo;
}

// Pack W[OUT][K] f32 -> bf16 B-fragment order
__global__ void k_pack_b(const float* __restrict__ W, u16* __restrict__ Bp, int OUT, int K){
  int t = blockIdx.x*256 + threadIdx.x;
  if (t >= OUT*K) return;
  int j = t & 7;
  int l = (t >> 3) & 63;
  int rest = t >> 9;
  int nks = K >> 5;
  int ks = rest % nks, c = rest / nks;
  int col = c*16 + (l & 15);
  int k = ks*32 + (l >> 4)*8 + j;
  Bp[t] = f2bf(W[(size_t)col*K + k]);
}

// Pack W[256][ldw] (logical K padded 78 -> 96) -> bf16 B-fragment order, zeros past FN
__global__ void k_pack_b96(const float* __restrict__ W, int ldw, u16* __restrict__ Bp){
  int t = blockIdx.x*256 + threadIdx.x;
  if (t >= 256*96) return;
  int j = t & 7;
  int l = (t >> 3) & 63;
  int rest = t >> 9;
  int ks = rest % 3, c = rest / 3;
  int col = c*16 + (l & 15);
  int k = ks*32 + (l >> 4)*8 + j;
  Bp[t] = (k < FN) ? f2bf(W[(size_t)col*ldw + k]) : (u16)0;
}

// Pack r,z gates of (Wih,Whh) into one K=512 B-matrix, r/z interleaved per 16-col group
__global__ void k_pack_rz(const float* __restrict__ Wih, const float* __restrict__ Whh,
                          u16* __restrict__ Bp){
  int t = blockIdx.x*256 + threadIdx.x;   // grid covers 512*512
  int j = t & 7;
  int l = (t >> 3) & 63;
  int rest = t >> 9;
  int ks = rest & 15, c = rest >> 4;      // nks = 16
  int srcrow = (c & 1)*256 + (c >> 1)*16 + (l & 15);
  int k = ks*32 + (l >> 4)*8 + j;
  float v = (k < 256) ? Wih[(size_t)srcrow*GD + k] : Whh[(size_t)srcrow*GD + (k - 256)];
  Bp[t] = f2bf(v);
}

// ---- fused dual node projection via MFMA (K=96, zero-padded from 78) ----
__global__ void __launch_bounds__(512)
k_np2_mfma(const float* __restrict__ nf,
           const u16* __restrict__ BpA, const float* __restrict__ bA,
           const u16* __restrict__ BpB, const float* __restrict__ bB,
           u16* __restrict__ hv, u16* __restrict__ Pb, int N){
  int tid = threadIdx.x;
  int wv = __builtin_amdgcn_readfirstlane(tid >> 6);
  int lane = tid & 63;
  int m = lane & 15, kg = lane >> 4;
  int r0 = blockIdx.x*64;
  f32x4 accA[2][4], accB[2][4];
  #pragma unroll
  for (int t=0;t<2;t++)
    #pragma unroll
    for (int rt=0;rt<4;rt++){ accA[t][rt] = (f32x4)(0.f); accB[t][rt] = (f32x4)(0.f); }
  #pragma unroll
  for (int ks=0; ks<3; ks++){
    int koff = ks*32 + kg*8;
    bf16x8 a[4];
    #pragma unroll
    for (int rt=0; rt<4; rt++){
      int row = r0 + rt*16 + m;
      if (row > N-1) row = N-1;
      const float* base = nf + (size_t)row*FN;
      #pragma unroll
      for (int q=0;q<8;q++){
        int k = koff + q;
        a[rt][q] = (short)((k < FN) ? f2bf(base[k]) : (u16)0);
      }
    }
    #pragma unroll
    for (int t=0;t<2;t++){
      int c = wv*2 + t;
      bf16x8 bva = *(const bf16x8*)&BpA[(size_t)((c*3 + ks)*64 + lane)*8];
      bf16x8 bvb = *(const bf16x8*)&BpB[(size_t)((c*3 + ks)*64 + lane)*8];
      #pragma unroll
      for (int rt=0; rt<4; rt++){
        accA[t][rt] = __builtin_amdgcn_mfma_f32_16x16x32_bf16(a[rt], bva, accA[t][rt], 0, 0, 0);
        accB[t][rt] = __builtin_amdgcn_mfma_f32_16x16x32_bf16(a[rt], bvb, accB[t][rt], 0, 0, 0);
      }
    }
  }
  #pragma unroll
  for (int t=0;t<2;t++){
    int col = wv*32 + t*16 + m;
    float ba = bA[col], bb = bB[col];
    #pragma unroll
    for (int rt=0; rt<4; rt++){
      #pragma unroll
      for (int i=0;i<4;i++){
        int row = r0 + rt*16 + kg*4 + i;
        if (row < N){
          hv[(size_t)row*GD + col] = f2bf(lrelu_(accA[t][rt][i] + ba));
          Pb[(size_t)row*GD + col] = f2bf(accB[t][rt][i] + bb);
        }
      }
    }
  }
}

// ---- per-node dot kernels ----
__global__ void k_dot2_bf16(const u16* __restrict__ rows, const float* __restrict__ wv,
                            float* __restrict__ za, float* __restrict__ zb, int N){
  int wav = threadIdx.x >> 6, lane = threadIdx.x & 63;
  int i = blockIdx.x*4 + wav;
  if (i >= N) return;
  int c0 = lane*4;
  ushort4 r4 = *(const ushort4*)&rows[(size_t)i*GD + c0];
  float4 wa = *(const float4*)&wv[c0];
  float4 wb = *(const float4*)&wv[GD + c0];
  float v0 = bf2f(r4.x), v1 = bf2f(r4.y), v2 = bf2f(r4.z), v3 = bf2f(r4.w);
  float va = v0*wa.x + v1*wa.y + v2*wa.z + v3*wa.w;
  float vb = v0*wb.x + v1*wb.y + v2*wb.z + v3*wb.w;
  #pragma unroll
  for (int off=32; off; off>>=1){ va += __shfl_down(va, off); vb += __shfl_down(vb, off); }
  if (lane == 0){ za[i] = va; zb[i] = vb; }
}

__global__ void k_dot1_bf16(const u16* __restrict__ rows, const float* __restrict__ wv,
                            float* __restrict__ z, int N){
  int wav = threadIdx.x >> 6, lane = threadIdx.x & 63;
  int i = blockIdx.x*4 + wav;
  if (i >= N) return;
  int c0 = lane*4;
  ushort4 r4 = *(const ushort4*)&rows[(size_t)i*GD + c0];
  float4 wa = *(const float4*)&wv[c0];
  float va = bf2f(r4.x)*wa.x + bf2f(r4.y)*wa.y + bf2f(r4.z)*wa.z + bf2f(r4.w)*wa.w;
  #pragma unroll
  for (int off=32; off; off>>=1) va += __shfl_down(va, off);
  if (lane == 0) z[i] = va;
}

__global__ void k_dotg_relu(const float* __restrict__ g, const float* __restrict__ wv,
                            float* __restrict__ zg, int B){
  int wav = threadIdx.x >> 6, lane = threadIdx.x & 63;
  int i = blockIdx.x*4 + wav;
  if (i >= B) return;
  int c0 = lane*4;
  float4 gv = *(const float4*)&g[(size_t)i*GD + c0];
  float4 wa = *(const float4*)&wv[c0];
  float va = fmaxf(gv.x,0.f)*wa.x + fmaxf(gv.y,0.f)*wa.y + fmaxf(gv.z,0.f)*wa.z + fmaxf(gv.w,0.f)*wa.w;
  #pragma unroll
  for (int off=32; off; off>>=1) va += __shfl_down(va, off);
  if (lane == 0) zg[i] = va;
}

// ---- per-edge he1 + logit, fully parallel, dst-sorted output slots ----
// wave handles 8 consecutive sorted slots; iterations independent (no rescale chain)
__global__ void __launch_bounds__(256)
k_he1s(const u16* __restrict__ P, const float* __restrict__ za,
       const int* __restrict__ order, const int* __restrict__ src, const int* __restrict__ dst,
       const float* __restrict__ ef, const float* __restrict__ Wpe1,
       const float* __restrict__ bpe1, const float* __restrict__ Wpe2,
       const float* __restrict__ bpe2, u16* __restrict__ he1s, float* __restrict__ lg, int E){
  int wv = threadIdx.x >> 6, lane = threadIdx.x & 63;
  int jbase = (blockIdx.x*4 + wv)*8;
  if (jbase >= E) return;
  int c0 = lane*4;
  float wb0 = Wpe2[GD+c0], wb1 = Wpe2[GD+c0+1], wb2 = Wpe2[GD+c0+2], wb3 = Wpe2[GD+c0+3];
  float bp0 = bpe1[c0], bp1 = bpe1[c0+1], bp2 = bpe1[c0+2], bp3 = bpe1[c0+3];
  float wk0[FE], wk1[FE], wk2[FE], wk3[FE];
  #pragma unroll
  for (int k=0;k<FE;k++){
    wk0[k] = Wpe1[(size_t)(c0+0)*(FN+FE) + FN + k];
    wk1[k] = Wpe1[(size_t)(c0+1)*(FN+FE) + FN + k];
    wk2[k] = Wpe1[(size_t)(c0+2)*(FN+FE) + FN + k];
    wk3[k] = Wpe1[(size_t)(c0+3)*(FN+FE) + FN + k];
  }
  float b2 = bpe2[0];
  for (int jj=0; jj<8; jj++){
    int j = jbase + jj; if (j >= E) break;
    int e = order[j];
    int sn = src[e], d = dst[e];
    ushort4 p4 = *(const ushort4*)&P[(size_t)sn*GD + c0];
    const float* efp = &ef[(size_t)e*FE];
    float efv[FE];
    #pragma unroll
    for (int k=0;k<FE;k++) efv[k] = efp[k];
    float h0 = bf2f(p4.x)+bp0, h1 = bf2f(p4.y)+bp1, h2 = bf2f(p4.z)+bp2, h3 = bf2f(p4.w)+bp3;
    #pragma unroll
    for (int k=0;k<FE;k++){
      h0 += wk0[k]*efv[k]; h1 += wk1[k]*efv[k]; h2 += wk2[k]*efv[k]; h3 += wk3[k]*efv[k];
    }
    h0 = lrelu_(h0); h1 = lrelu_(h1); h2 = lrelu_(h2); h3 = lrelu_(h3);
    ushort4 o;
    o.x = f2bf(h0); o.y = f2bf(h1); o.z = f2bf(h2); o.w = f2bf(h3);
    *(ushort4*)&he1s[(size_t)j*GD + c0] = o;
    float part = h0*wb0 + h1*wb1 + h2*wb2 + h3*wb3;
    #pragma unroll
    for (int off=32; off; off>>=1) part += __shfl_down(part, off);
    if (lane == 0) lg[j] = lrelu_(part + za[d] + b2);
  }
}

// ---- ctx aggregation: two-pass over contiguous sorted he1s rows ----
__global__ void __launch_bounds__(256)
k_ctx_agg(const u16* __restrict__ he1s, const float* __restrict__ lg,
          const int* __restrict__ rowptr, u16* __restrict__ wc,
          float* __restrict__ sdeg, int N){
  int wv = threadIdx.x >> 6, lane = threadIdx.x & 63;
  int d = blockIdx.x*4 + wv;
  if (d >= N) return;
  int j0 = rowptr[d], j1 = rowptr[d+1];
  int c0 = lane*4;
  float M = -1e30f;
  for (int j=j0; j<j1; j++) M = fmaxf(M, lg[j]);
  float s = 0.f;
  float a0=0.f, a1=0.f, a2=0.f, a3=0.f;
  for (int j=j0; j<j1; j++){
    float p = __expf(lg[j] - M);
    ushort4 h4 = *(const ushort4*)&he1s[(size_t)j*GD + c0];
    s += p;
    a0 += p*bf2f(h4.x);
    a1 += p*bf2f(h4.y);
    a2 += p*bf2f(h4.z);
    a3 += p*bf2f(h4.w);
  }
  float inv = (j1 > j0) ? 1.f/s : 0.f;
  ushort4 o;
  o.x = f2bf(a0*inv); o.y = f2bf(a1*inv); o.z = f2bf(a2*inv); o.w = f2bf(a3*inv);
  *(ushort4*)&wc[(size_t)d*GD + c0] = o;
  if (lane == 0) sdeg[d] = (j1 > j0) ? 1.f : 0.f;
}

// ---- GetContext fused (fallback when ws too small for he1s buffer) ----
__global__ void __launch_bounds__(256)
k_ctx_fused(const u16* __restrict__ P, const float* __restrict__ za,
            const int* __restrict__ order, const int* __restrict__ rowptr,
            const int* __restrict__ src, const float* __restrict__ ef,
            const float* __restrict__ Wpe1, const float* __restrict__ bpe1,
            const float* __restrict__ Wpe2, const float* __restrict__ bpe2,
            u16* __restrict__ wc, float* __restrict__ sdeg, int N){
  int wv = threadIdx.x >> 6, lane = threadIdx.x & 63;
  int d = blockIdx.x*4 + wv;
  if (d >= N) return;
  int j0 = rowptr[d], j1 = rowptr[d+1];
  int c0 = lane*4;
  float wb0 = Wpe2[GD+c0], wb1 = Wpe2[GD+c0+1], wb2 = Wpe2[GD+c0+2], wb3 = Wpe2[GD+c0+3];
  float bp0 = bpe1[c0], bp1 = bpe1[c0+1], bp2 = bpe1[c0+2], bp3 = bpe1[c0+3];
  float wk0[FE], wk1[FE], wk2[FE], wk3[FE];
  #pragma unroll
  for (int k=0;k<FE;k++){
    wk0[k] = Wpe1[(size_t)(c0+0)*(FN+FE) + FN + k];
    wk1[k] = Wpe1[(size_t)(c0+1)*(FN+FE) + FN + k];
    wk2[k] = Wpe1[(size_t)(c0+2)*(FN+FE) + FN + k];
    wk3[k] = Wpe1[(size_t)(c0+3)*(FN+FE) + FN + k];
  }
  float zad = za[d] + bpe2[0];
  float m = -1e30f, s = 0.f;
  float a0=0.f, a1=0.f, a2=0.f, a3=0.f;
  for (int j=j0; j<j1; j++){
    int e = order[j];
    int sn = src[e];
    ushort4 p4 = *(const ushort4*)&P[(size_t)sn*GD + c0];
    const float* efp = &ef[(size_t)e*FE];
    float efv[FE];
    #pragma unroll
    for (int k=0;k<FE;k++) efv[k] = efp[k];
    float h0 = bf2f(p4.x)+bp0, h1 = bf2f(p4.y)+bp1, h2 = bf2f(p4.z)+bp2, h3 = bf2f(p4.w)+bp3;
    #pragma unroll
    for (int k=0;k<FE;k++){
      h0 += wk0[k]*efv[k]; h1 += wk1[k]*efv[k]; h2 += wk2[k]*efv[k]; h3 += wk3[k]*efv[k];
    }
    h0 = lrelu_(h0); h1 = lrelu_(h1); h2 = lrelu_(h2); h3 = lrelu_(h3);
    float part = h0*wb0 + h1*wb1 + h2*wb2 + h3*wb3;
    #pragma unroll
    for (int off=32; off; off>>=1) part += __shfl_down(part, off);
    float l = lrelu_(part + zad);
    l = __shfl(l, 0);
    float mn = fmaxf(m, l);
    float sc = __expf(m - mn);
    float p  = __expf(l - mn);
    s = s*sc + p;
    a0 = a0*sc + p*h0; a1 = a1*sc + p*h1; a2 = a2*sc + p*h2; a3 = a3*sc + p*h3;
    m = mn;
  }
  float inv = (j1 > j0) ? 1.f/s : 0.f;
  ushort4 o;
  o.x = f2bf(a0*inv); o.y = f2bf(a1*inv); o.z = f2bf(a2*inv); o.w = f2bf(a3*inv);
  *(ushort4*)&wc[(size_t)d*GD + c0] = o;
  if (lane == 0) sdeg[d] = (j1 > j0) ? 1.f : 0.f;
}

// ---- GNN layer fused, TWO-PASS ----
__global__ void __launch_bounds__(256)
k_gnn_fused(const u16* __restrict__ hv, const float* __restrict__ za, const float* __restrict__ zb,
            const int* __restrict__ order, const int* __restrict__ rowptr,
            const int* __restrict__ src, const float* __restrict__ bias,
            u16* __restrict__ cw, int N){
  int wv = threadIdx.x >> 6, lane = threadIdx.x & 63;
  int d = blockIdx.x*4 + wv;
  if (d >= N) return;
  int j0 = rowptr[d], j1 = rowptr[d+1];
  int c0 = lane*4;
  float zad = za[d] + bias[0];
  float M = -1e30f;
  for (int j=j0; j<j1; j++){
    int sn = src[order[j]];
    M = fmaxf(M, lrelu_(zad + zb[sn]));
  }
  float s = 0.f;
  float a0=0.f, a1=0.f, a2=0.f, a3=0.f;
  for (int j=j0; j<j1; j++){
    int e = order[j];
    int sn = src[e];
    float p = __expf(lrelu_(zad + zb[sn]) - M);
    ushort4 r4 = *(const ushort4*)&hv[(size_t)sn*GD + c0];
    s += p;
    a0 += p*bf2f(r4.x);
    a1 += p*bf2f(r4.y);
    a2 += p*bf2f(r4.z);
    a3 += p*bf2f(r4.w);
  }
  float inv = (j1 > j0) ? 1.f/s : 0.f;
  ushort4 o;
  o.x = f2bf(elu_(a0*inv)); o.y = f2bf(elu_(a1*inv));
  o.z = f2bf(elu_(a2*inv)); o.w = f2bf(elu_(a3*inv));
  *(ushort4*)&cw[(size_t)d*GD + c0] = o;
}

// ---- readout fused ----
__global__ void __launch_bounds__(256)
k_ro_fused(const u16* __restrict__ hv, const float* __restrict__ zg, const float* __restrict__ zh,
           const int* __restrict__ gpb, const float* __restrict__ bias,
           float* __restrict__ gr, int B){
  int b = blockIdx.x, tid = threadIdx.x;
  int i0 = gpb[b], i1 = gpb[b+1];
  float zgb = zg[b] + bias[0];
  __shared__ float red[256];
  float lm = -1e30f;
  for (int i = i0 + tid; i < i1; i += 256) lm = fmaxf(lm, lrelu_(zgb + zh[i]));
  red[tid] = lm; __syncthreads();
  for (int d2=128; d2; d2>>=1){ if (tid < d2) red[tid] = fmaxf(red[tid], red[tid+d2]); __syncthreads(); }
  float M = red[0]; __syncthreads();
  float ls = 0.f;
  for (int i = i0 + tid; i < i1; i += 256) ls += __expf(lrelu_(zgb + zh[i]) - M);
  red[tid] = ls; __syncthreads();
  for (int d2=128; d2; d2>>=1){ if (tid < d2) red[tid] += red[tid+d2]; __syncthreads(); }
  float S = red[0];
  float acc = 0.f;
  for (int i = i0; i < i1; i++){
    float p = __expf(lrelu_(zgb + zh[i]) - M);
    acc += p * bf2f(hv[(size_t)i*GD + tid]);
  }
  gr[(size_t)b*GD + tid] = (i1 > i0) ? acc/S : 0.f;
}

__global__ void k_segsum_sorted(const u16* __restrict__ h, const int* __restrict__ gpb,
                                float* __restrict__ g, int B){
  int b = blockIdx.x, tid = threadIdx.x;
  int i0 = gpb[b], i1 = gpb[b+1];
  float acc = 0.f;
  for (int i = i0; i < i1; i++) acc += bf2f(h[(size_t)i*GD + tid]);
  g[(size_t)b*GD + tid] = acc;
}

// ---- 32-row MFMA GRU with fused r/z gates (K=512 concat) ----
__global__ void __launch_bounds__(512)
k_gru_mfma32(const u16* __restrict__ x, const u16* __restrict__ hprev,
             const u16* __restrict__ rzp, const u16* __restrict__ nip, const u16* __restrict__ nhp,
             const float* __restrict__ bih, const float* __restrict__ bhh,
             u16* __restrict__ hout, int R){
  int tid = threadIdx.x;
  int wv = __builtin_amdgcn_readfirstlane(tid >> 6);
  int lane = tid & 63;
  int m = lane & 15, kg = lane >> 4;
  int r0 = blockIdx.x*32;   // R must be a multiple of 32 (100000 = 3125*32)

  f32x4 arz[2][4], ani[2][2], anh[2][2];
  #pragma unroll
  for (int rt=0;rt<2;rt++){
    #pragma unroll
    for (int t=0;t<4;t++) arz[rt][t] = (f32x4)(0.f);
    #pragma unroll
    for (int t=0;t<2;t++){ ani[rt][t] = (f32x4)(0.f); anh[rt][t] = (f32x4)(0.f); }
  }

  #pragma unroll
  for (int ks=0; ks<8; ks++){
    int koff = ks*32 + kg*8;
    bf16x8 ax[2], ah[2];
    #pragma unroll
    for (int rt=0; rt<2; rt++){
      int row = r0 + rt*16 + m;
      ax[rt] = *(const bf16x8*)&x[(size_t)row*GD + koff];
      ah[rt] = *(const bf16x8*)&hprev[(size_t)row*GD + koff];
    }
    #pragma unroll
    for (int t=0;t<4;t++){
      int c = wv*4 + t;
      bf16x8 bx = *(const bf16x8*)&rzp[(size_t)((c*16 + ks    )*64 + lane)*8];
      bf16x8 bh = *(const bf16x8*)&rzp[(size_t)((c*16 + ks + 8)*64 + lane)*8];
      #pragma unroll
      for (int rt=0; rt<2; rt++){
        arz[rt][t] = __builtin_amdgcn_mfma_f32_16x16x32_bf16(ax[rt], bx, arz[rt][t], 0, 0, 0);
        arz[rt][t] = __builtin_amdgcn_mfma_f32_16x16x32_bf16(ah[rt], bh, arz[rt][t], 0, 0, 0);
      }
    }
    #pragma unroll
    for (int t=0;t<2;t++){
      int c = wv*2 + t;
      bf16x8 bi = *(const bf16x8*)&nip[(size_t)((c*8 + ks)*64 + lane)*8];
      bf16x8 bh = *(const bf16x8*)&nhp[(size_t)((c*8 + ks)*64 + lane)*8];
      #pragma unroll
      for (int rt=0; rt<2; rt++){
        ani[rt][t] = __builtin_amdgcn_mfma_f32_16x16x32_bf16(ax[rt], bi, ani[rt][t], 0, 0, 0);
        anh[rt][t] = __builtin_amdgcn_mfma_f32_16x16x32_bf16(ah[rt], bh, anh[rt][t], 0, 0, 0);
      }
    }
  }

  #pragma unroll
  for (int g=0; g<2; g++){
    int ch = (wv*2 + g)*16 + m;
    float brz_r = bih[ch] + bhh[ch];
    float brz_z = bih[ch+GD] + bhh[ch+GD];
    float bin   = bih[ch+2*GD];
    float bhn   = bhh[ch+2*GD];
    #pragma unroll
    for (int rt=0; rt<2; rt++){
      #pragma unroll
      for (int i=0;i<4;i++){
        int row = r0 + rt*16 + kg*4 + i;
        float rr = sigm_(arz[rt][2*g  ][i] + brz_r);
        float zz = sigm_(arz[rt][2*g+1][i] + brz_z);
        float nn = tanhf(ani[rt][g][i] + bin + rr*(anh[rt][g][i] + bhn));
        float hp = bf2f(hprev[(size_t)row*GD + ch]);
        float o = (1.f - zz)*nn + zz*hp;
        hout[(size_t)row*GD + ch] = f2bf(fmaxf(o, 0.f));
      }
    }
  }
}

// ---- 64-row MFMA projection: Y = X@W^T + b, optional mask+elu epilogue ----
template<int DO_ELU>
__global__ void __launch_bounds__(512)
k_proj_mfma64(const u16* __restrict__ X, const u16* __restrict__ Wp,
              const float* __restrict__ b, u16* __restrict__ Y, int R,
              const float* __restrict__ mask){
  int tid = threadIdx.x;
  int wv = __builtin_amdgcn_readfirstlane(tid >> 6);
  int lane = tid & 63;
  int m = lane & 15, kg = lane >> 4;
  int r0 = blockIdx.x*64;
  f32x4 acc[2][4];
  #pragma unroll
  for (int t=0;t<2;t++)
    #pragma unroll
    for (int rt=0;rt<4;rt++) acc[t][rt] = (f32x4)(0.f);
  #pragma unroll
  for (int ks=0; ks<8; ks++){
    int koff = ks*32 + kg*8;
    bf16x8 a[4];
    #pragma unroll
    for (int rt=0; rt<4; rt++){
      int row = r0 + rt*16 + m;
      if (row > R-1) row = R-1;
      a[rt] = *(const bf16x8*)&X[(size_t)row*GD + koff];
    }
    #pragma unroll
    for (int t=0;t<2;t++){
      int c = wv*2 + t;
      bf16x8 bv = *(const bf16x8*)&Wp[(size_t)((c*8 + ks)*64 + lane)*8];
      #pragma unroll
      for (int rt=0; rt<4; rt++)
        acc[t][rt] = __builtin_amdgcn_mfma_f32_16x16x32_bf16(a[rt], bv, acc[t][rt], 0, 0, 0);
    }
  }
  #pragma unroll
  for (int t=0;t<2;t++){
    int col = wv*32 + t*16 + m;
    float bb = b[col];
    #pragma unroll
    for (int rt=0; rt<4; rt++){
      #pragma unroll
      for (int i=0;i<4;i++){
        int row = r0 + rt*16 + kg*4 + i;
        if (row < R){
          float v = acc[t][rt][i] + bb;
          if (DO_ELU){
            float mk = (mask[row] > 0.f) ? 1.f : 0.f;
            v = elu_(v*mk);
          }
          Y[(size_t)row*GD + col] = f2bf(v);
        }
      }
    }
  }
}

// ---- 16-row MFMA GRU for readout (f32 in/out, elu applied here) ----
__global__ void __launch_bounds__(256)
k_gru_mfma_f32(const float* __restrict__ x, const float* __restrict__ hprev,
               const u16* __restrict__ Wihp, const u16* __restrict__ Whhp,
               const float* __restrict__ bih, const float* __restrict__ bhh,
               float* __restrict__ hout, int R){
  int tid = threadIdx.x;
  int wave = __builtin_amdgcn_readfirstlane(tid >> 6);
  int lane = tid & 63;
  int m = lane & 15, kg = lane >> 4;
  int r0 = blockIdx.x*16;

  f32x4 agi[3][4], agh[3][4];
  #pragma unroll
  for (int g=0;g<3;g++)
    #pragma unroll
    for (int t=0;t<4;t++){ agi[g][t] = (f32x4)(0.f); agh[g][t] = (f32x4)(0.f); }

  #pragma unroll
  for (int ks=0; ks<8; ks++){
    int koff = ks*32 + kg*8;
    const float* xp = x + (size_t)(r0 + m)*GD + koff;
    float4 x0 = *(const float4*)xp;
    float4 x1 = *(const float4*)(xp+4);
    bf16x8 ax;
    ax[0]=(short)f2bf(elu_(x0.x)); ax[1]=(short)f2bf(elu_(x0.y));
    ax[2]=(short)f2bf(elu_(x0.z)); ax[3]=(short)f2bf(elu_(x0.w));
    ax[4]=(short)f2bf(elu_(x1.x)); ax[5]=(short)f2bf(elu_(x1.y));
    ax[6]=(short)f2bf(elu_(x1.z)); ax[7]=(short)f2bf(elu_(x1.w));
    const float* hr = hprev + (size_t)(r0 + m)*GD + koff;
    float4 h0 = *(const float4*)hr;
    float4 h1 = *(const float4*)(hr+4);
    bf16x8 ah;
    ah[0]=(short)f2bf(h0.x); ah[1]=(short)f2bf(h0.y); ah[2]=(short)f2bf(h0.z); ah[3]=(short)f2bf(h0.w);
    ah[4]=(short)f2bf(h1.x); ah[5]=(short)f2bf(h1.y); ah[6]=(short)f2bf(h1.z); ah[7]=(short)f2bf(h1.w);
    #pragma unroll
    for (int g=0;g<3;g++){
      #pragma unroll
      for (int t=0;t<4;t++){
        int c = g*16 + wave*4 + t;
        bf16x8 bi = *(const bf16x8*)&Wihp[(size_t)((c*8 + ks)*64 + lane)*8];
        bf16x8 bh = *(const bf16x8*)&Whhp[(size_t)((c*8 + ks)*64 + lane)*8];
        agi[g][t] = __builtin_amdgcn_mfma_f32_16x16x32_bf16(ax, bi, agi[g][t], 0, 0, 0);
        agh[g][t] = __builtin_amdgcn_mfma_f32_16x16x32_bf16(ah, bh, agh[g][t], 0, 0, 0);
      }
    }
  }
  #pragma unroll
  for (int t=0;t<4;t++){
    int col = wave*64 + t*16 + m;
    float bir = bih[col],      bhr = bhh[col];
    float biz = bih[col+GD],   bhz = bhh[col+GD];
    float bin = bih[col+2*GD], bhn = bhh[col+2*GD];
    #pragma unroll
    for (int i=0;i<4;i++){
      int row = r0 + kg*4 + i;
      float rr = sigm_(agi[0][t][i] + bir + agh[0][t][i] + bhr);
      float zz = sigm_(agi[1][t][i] + biz + agh[1][t][i] + bhz);
      float nn = tanhf(agi[2][t][i] + bin + rr*(agh[2][t][i] + bhn));
      float hp = hprev[(size_t)row*GD + col];
      float o = (1.f - zz)*nn + zz*hp;
      hout[(size_t)row*GD + col] = fmaxf(o, 0.f);
    }
  }
}

__global__ void k_layernorm(const float* __restrict__ gb, const float* __restrict__ gamma,
                            const float* __restrict__ beta, float* __restrict__ outb){
  int r = blockIdx.x, j = threadIdx.x;
  float v = gb[(size_t)r*GD + j];
  float s1 = v, s2 = v*v;
  #pragma unroll
  for (int off=32; off; off>>=1){ s1 += __shfl_down(s1, off); s2 += __shfl_down(s2, off); }
  __shared__ float r1[4], r2[4];
  int wv = j >> 6, lane = j & 63;
  if (lane == 0){ r1[wv] = s1; r2[wv] = s2; }
  __syncthreads();
  float S1 = r1[0]+r1[1]+r1[2]+r1[3];
  float S2 = r2[0]+r2[1]+r2[2]+r2[3];
  float mu = S1/(float)GD;
  float var = fmaxf(S2/(float)GD - mu*mu, 0.f);
  outb[(size_t)r*GD + j] = (v - mu)/sqrtf(var + 1e-5f)*gamma[j] + beta[j];
}

extern "C" void kernel_launch(void* const* d_in, const int* in_sizes, int n_in,
                              void* d_out, int out_size, void* d_ws, size_t ws_size,
                              hipStream_t stream){
  const float* node_feats = (const float*)d_in[0];
  const float* edge_feats = (const float*)d_in[1];
  const int*   src        = (const int*)d_in[2];
  const int*   dst        = (const int*)d_in[3];
  const int*   node_graph = (const int*)d_in[4];
  const float* W_pn   = (const float*)d_in[5];
  const float* b_pn   = (const float*)d_in[6];
  const float* W_pe1  = (const float*)d_in[7];
  const float* b_pe1  = (const float*)d_in[8];
  const float* W_pe2  = (const float*)d_in[9];
  const float* b_pe2  = (const float*)d_in[10];
  const float* W_et   = (const float*)d_in[11];
  const float* b_et   = (const float*)d_in[12];
  const float* g0_Wih = (const float*)d_in[13];
  const float* g0_Whh = (const float*)d_in[14];
  const float* g0_bih = (const float*)d_in[15];
  const float* g0_bhh = (const float*)d_in[16];
  const float* gnn_W_pe = (const float*)d_in[17];
  const float* gnn_b_pe = (const float*)d_in[18];
  const float* gnn_W_pn = (const float*)d_in[19];
  const float* gnn_b_pn = (const float*)d_in[20];
  const float* gnn_Wih  = (const float*)d_in[21];
  const float* gnn_Whh  = (const float*)d_in[22];
  const float* gnn_bih  = (const float*)d_in[23];
  const float* gnn_bhh  = (const float*)d_in[24];
  const float* ro_W_cl = (const float*)d_in[25];
  const float* ro_b_cl = (const float*)d_in[26];
  const float* ro_W_pn = (const float*)d_in[27];
  const float* ro_b_pn = (const float*)d_in[28];
  const float* ro_Wih  = (const float*)d_in[29];
  const float* ro_Whh  = (const float*)d_in[30];
  const float* ro_bih  = (const float*)d_in[31];
  const float* ro_bhh  = (const float*)d_in[32];
  const float* ln_gamma = (const float*)d_in[33];
  const float* ln_beta  = (const float*)d_in[34];
  float* outp = (float*)d_out;

  const int NBLK = (NN + 255)/256;

  // ---- workspace layout (he1s LAST so base fits even if ws is tight) ----
  char* w = (char*)d_ws;
  size_t need = 0;
  float* gbuf  = (float*)(w + need); need += (size_t)NB*GD*4;
  float* grbuf = (float*)(w + need); need += (size_t)NB*GD*4;
  float* za    = (float*)(w + need); need += (size_t)NN*4;
  float* zb    = (float*)(w + need); need += (size_t)NN*4;
  float* zg    = (float*)(w + need); need += (size_t)NB*4;
  float* sdeg  = (float*)(w + need); need += (size_t)NN*4;
  float* lg    = (float*)(w + need); need += (size_t)NE*4;
  int*   cnt    = (int*)(w + need); need += (size_t)NN*4;
  int*   rowptr = (int*)(w + need); need += (size_t)(NN+1)*4;
  int*   cursor = (int*)(w + need); need += (size_t)NN*4;
  int*   order  = (int*)(w + need); need += (size_t)NE*4;
  int*   gpb    = (int*)(w + need); need += (size_t)(NB+1)*4;
  int*   btot   = (int*)(w + need); need += (size_t)512*4;
  int*   boff   = (int*)(w + need); need += (size_t)512*4;
  u16*   hbuf = (u16*)(w + need); need += (size_t)NN*GD*2;
  u16*   htmp = (u16*)(w + need); need += (size_t)NN*GD*2;
  u16*   cwb  = (u16*)(w + need); need += (size_t)NN*GD*2;
  u16*   dbuf = (u16*)(w + need); need += (size_t)NN*GD*2;
  u16* pGruN = (u16*)(w + need); need += (size_t)3*393216*2;
  u16* pGruR = (u16*)(w + need); need += (size_t)4*196608*2;
  u16* pPn  = (u16*)(w + need); need += (size_t)4*GD*GD*2;
  u16* pEt  = (u16*)(w + need); need += (size_t)GD*GD*2;
  u16* pNp  = (u16*)(w + need); need += (size_t)2*256*96*2;
  if (ws_size < need) return;
  u16* he1s = (u16*)(w + need);
  bool use_sorted = (ws_size >= need + (size_t)NE*GD*2);
  u16* Pbuf   = hbuf;
  u16* hv_new = htmp;

  const size_t LW = 393216;
  const size_t OW = 196608;
  const size_t PW = (size_t)GD*GD;
  const size_t NPW = (size_t)256*96;
  const int G64 = (NN + 63)/64;
  const int G32 = NN/32;

  // ---- CSR build + graph rowptr ----
  k_zero<<<64, 256, 0, stream>>>((float*)cnt, (size_t)NN);
  k_count<<<(NE+255)/256, 256, 0, stream>>>(dst, cnt, NE);
  k_scan1<<<NBLK, 256, 0, stream>>>(cnt, cnt, btot, NN);
  k_scan2<<<1, 512, 0, stream>>>(btot, boff, NBLK);
  k_scan3<<<NBLK, 256, 0, stream>>>(cnt, boff, rowptr, NN);
  k_cursor<<<NBLK, 256, 0, stream>>>(rowptr, cursor, NN);
  k_fill<<<(NE+255)/256, 256, 0, stream>>>(dst, cursor, order, NE);
  k_gpb<<<(NB+256)/256, 256, 0, stream>>>(node_graph, gpb, NN, NB);

  // ---- weight packing ----
  const float* wihs[3] = { g0_Wih, gnn_Wih, gnn_Wih + (size_t)3*GD*GD };
  const float* whhs[3] = { g0_Whh, gnn_Whh, gnn_Whh + (size_t)3*GD*GD };
  for (int l=0;l<3;l++){
    k_pack_rz<<<1024, 256, 0, stream>>>(wihs[l], whhs[l], pGruN + l*LW);
    k_pack_b<<<256, 256, 0, stream>>>(wihs[l] + (size_t)512*GD, pGruN + l*LW + 262144, 256, GD);
    k_pack_b<<<256, 256, 0, stream>>>(whhs[l] + (size_t)512*GD, pGruN + l*LW + 327680, 256, GD);
  }
  for (int t=0;t<NT;t++){
    k_pack_b<<<768, 256, 0, stream>>>(ro_Wih + (size_t)t*3*GD*GD, pGruR + (2*t)*OW, 768, GD);
    k_pack_b<<<768, 256, 0, stream>>>(ro_Whh + (size_t)t*3*GD*GD, pGruR + (2*t+1)*OW, 768, GD);
  }
  for (int l=0;l<NL;l++)
    k_pack_b<<<256, 256, 0, stream>>>(gnn_W_pn + (size_t)l*GD*GD, pPn + l*PW, GD, GD);
  for (int t=0;t<NT;t++)
    k_pack_b<<<256, 256, 0, stream>>>(ro_W_pn + (size_t)t*GD*GD, pPn + (2+t)*PW, GD, GD);
  k_pack_b<<<256, 256, 0, stream>>>(W_et, pEt, GD, GD);
  k_pack_b96<<<96, 256, 0, stream>>>(W_pn, FN, pNp);
  k_pack_b96<<<96, 256, 0, stream>>>(W_pe1, FN+FE, pNp + NPW);

  // ---------------- GetContext ----------------
  k_np2_mfma<<<G64, 512, 0, stream>>>(node_feats, pNp, b_pn, pNp + NPW, b_pe1,
                                      hv_new, Pbuf, NN);
  k_dot1_bf16<<<(NN+3)/4, 256, 0, stream>>>(hv_new, W_pe2, za, NN);
  if (use_sorted){
    k_he1s<<<NE/32, 256, 0, stream>>>(Pbuf, za, order, src, dst, edge_feats,
                                      W_pe1, b_pe1, W_pe2, b_pe2, he1s, lg, NE);
    k_ctx_agg<<<(NN+3)/4, 256, 0, stream>>>(he1s, lg, rowptr, cwb, sdeg, NN);
  } else {
    k_ctx_fused<<<(NN+3)/4, 256, 0, stream>>>(Pbuf, za, order, rowptr, src, edge_feats,
                                              W_pe1, b_pe1, W_pe2, b_pe2, cwb, sdeg, NN);
  }
  k_proj_mfma64<1><<<G64, 512, 0, stream>>>(cwb, pEt, b_et, dbuf, NN, sdeg);
  k_gru_mfma32<<<G32, 512, 0, stream>>>(dbuf, hv_new, pGruN + 0*LW, pGruN + 0*LW + 262144,
                                        pGruN + 0*LW + 327680, g0_bih, g0_bhh, hbuf, NN);

  // ---------------- GNN layers ----------------
  for (int l=0; l<NL; l++){
    k_dot2_bf16<<<(NN+3)/4, 256, 0, stream>>>(hbuf, gnn_W_pe + (size_t)l*2*GD, za, zb, NN);
    k_proj_mfma64<0><<<G64, 512, 0, stream>>>(hbuf, pPn + l*PW, gnn_b_pn + (size_t)l*GD,
                                              htmp, NN, nullptr);
    k_gnn_fused<<<(NN+3)/4, 256, 0, stream>>>(htmp, za, zb, order, rowptr, src,
                                              gnn_b_pe + l, cwb, NN);
    k_gru_mfma32<<<G32, 512, 0, stream>>>(cwb, hbuf,
                                pGruN + (1+l)*LW, pGruN + (1+l)*LW + 262144, pGruN + (1+l)*LW + 327680,
                                gnn_bih + (size_t)l*3*GD, gnn_bhh + (size_t)l*3*GD, hbuf, NN);
  }

  // ---------------- Readout ----------------
  k_segsum_sorted<<<NB, 256, 0, stream>>>(hbuf, gpb, gbuf, NB);
  for (int t=0; t<NT; t++){
    k_dotg_relu<<<(NB+3)/4, 256, 0, stream>>>(gbuf, ro_W_cl + (size_t)t*2*GD, zg, NB);
    k_dot1_bf16<<<(NN+3)/4, 256, 0, stream>>>(hbuf, ro_W_cl + (size_t)t*2*GD + GD, za, NN);
    k_proj_mfma64<0><<<G64, 512, 0, stream>>>(hbuf, pPn + (2+t)*PW, ro_b_pn + (size_t)t*GD,
                                              htmp, NN, nullptr);
    k_ro_fused<<<NB, 256, 0, stream>>>(htmp, zg, za, gpb, ro_b_cl + t, grbuf, NB);
    k_gru_mfma_f32<<<NB/16, 256, 0, stream>>>(grbuf, gbuf,
                                pGruR + (2*t)*OW, pGruR + (2*t+1)*OW,
                                ro_bih + (size_t)t*3*GD, ro_bhh + (size_t)t*3*GD, gbuf, NB);
  }
  k_layernorm<<<NB, 256, 0, stream>>>(gbuf, ln_gamma, ln_beta, outp);
}